// Round 1
// baseline (1252.105 us; speedup 1.0000x reference)
//
#include <hip/hip_runtime.h>
#include <math.h>

#define BB 16
#define SS 512
#define DD 256
#define HH 8
#define HDIM 32
#define FFD 1024
#define NL 2
#define NSOUT 1024
#define SD (SS*DD)      // 131072
#define ROWS (BB*SS)    // 8192

__device__ __forceinline__ float wave_sum(float v) {
#pragma unroll
    for (int off = 32; off > 0; off >>= 1) v += __shfl_xor(v, off);
    return v;
}
__device__ __forceinline__ float wave_max(float v) {
#pragma unroll
    for (int off = 32; off > 0; off >>= 1) v = fmaxf(v, __shfl_xor(v, off));
    return v;
}

// ---------------- RoPE tables: cos/sin [S][16] ----------------
__global__ __launch_bounds__(256) void k_rope_table(float* ct, float* st) {
    int i = blockIdx.x * 256 + threadIdx.x;   // 8192 = 512*16
    if (i >= SS * 16) return;
    int s = i >> 4, f = i & 15;
    float invf = powf(10000.f, -(float)f / 16.f);
    float ang = (float)s * invf;
    ct[i] = cosf(ang);
    st[i] = sinf(ang);
}

// ---------------- input features + projection ----------------
__global__ __launch_bounds__(256) void k_input_proj(
    const float* __restrict__ values, const float* __restrict__ dib,
    const float* __restrict__ gamma, const float* __restrict__ mtyp,
    const float* __restrict__ in_w, const float* __restrict__ in_b,
    float* __restrict__ x) {
    int i = blockIdx.x * 256 + threadIdx.x;   // ROWS*DD
    int row = i >> 8, d = i & 255;
    float v = values[row];
    float f0 = (v >= 0.f) ? 1.f : -1.f;
    float f1 = fabsf(v);
    float f2 = gamma[row];
    float f3 = dib[row];
    float f4 = mtyp[row] * 2.f - 1.f;
    x[i] = f0 * in_w[d] + f1 * in_w[DD + d] + f2 * in_w[2 * DD + d]
         + f3 * in_w[3 * DD + d] + f4 * in_w[4 * DD + d] + in_b[d];
}

// ---------------- layernorm over D=256, one block per row ----------------
__global__ __launch_bounds__(256) void k_layernorm(
    const float* __restrict__ in, float* __restrict__ out,
    const float* __restrict__ sc, const float* __restrict__ bi) {
    int row = blockIdx.x;
    int t = threadIdx.x;
    float v = in[(size_t)row * DD + t];
    __shared__ float red[8];
    int wid = t >> 6, lane = t & 63;
    float s = wave_sum(v);
    if (lane == 0) red[wid] = s;
    __syncthreads();
    float mean = (red[0] + red[1] + red[2] + red[3]) * (1.f / DD);
    float dv = v - mean;
    float s2 = wave_sum(dv * dv);
    if (lane == 0) red[4 + wid] = s2;
    __syncthreads();
    float var = (red[4] + red[5] + red[6] + red[7]) * (1.f / DD);
    out[(size_t)row * DD + t] = dv * rsqrtf(var + 1e-5f) * sc[t] + bi[t];
}

// ---------------- generic fp32 GEMM: C[M,N] = A[M,K]@W[K,N] + bias ----------------
// optional exact GELU, optional residual add with per-row mask:
//   RES:  C[m,n] = res[m,n] + val * (mask ? mask[m]!=0 : 1)
template <bool GELU, bool RES>
__global__ __launch_bounds__(256) void k_gemm(
    const float* __restrict__ A, const float* __restrict__ W,
    const float* __restrict__ bias, float* __restrict__ C,
    int M, int N, int K,
    const float* __restrict__ res, const int* __restrict__ mask) {
    __shared__ float As[16][68];   // [k][m]
    __shared__ float Ws[16][68];   // [k][n]
    int t = threadIdx.x;
    int tx = t & 15, ty = t >> 4;
    int m0 = blockIdx.x * 64, n0 = blockIdx.y * 64;
    int lm = t >> 2;            // 0..63
    int lk = (t & 3) * 4;       // 0,4,8,12
    int wk = t >> 4;            // 0..15
    int wn = (t & 15) * 4;      // 0..60
    float c[4][4] = {};
    for (int k0 = 0; k0 < K; k0 += 16) {
        float4 av = *(const float4*)&A[(size_t)(m0 + lm) * K + k0 + lk];
        As[lk + 0][lm] = av.x; As[lk + 1][lm] = av.y;
        As[lk + 2][lm] = av.z; As[lk + 3][lm] = av.w;
        *(float4*)&Ws[wk][wn] = *(const float4*)&W[(size_t)(k0 + wk) * N + n0 + wn];
        __syncthreads();
#pragma unroll
        for (int kk = 0; kk < 16; ++kk) {
            float4 a4 = *(const float4*)&As[kk][ty * 4];
            float4 b4 = *(const float4*)&Ws[kk][tx * 4];
            const float aa[4] = {a4.x, a4.y, a4.z, a4.w};
            const float bb[4] = {b4.x, b4.y, b4.z, b4.w};
#pragma unroll
            for (int i = 0; i < 4; ++i)
#pragma unroll
                for (int j = 0; j < 4; ++j) c[i][j] += aa[i] * bb[j];
        }
        __syncthreads();
    }
#pragma unroll
    for (int i = 0; i < 4; ++i) {
        int m = m0 + ty * 4 + i;
        float mk = 1.f;
        if (RES && mask) mk = (mask[m] != 0) ? 1.f : 0.f;
        float4 o;
#pragma unroll
        for (int j = 0; j < 4; ++j) {
            float v = c[i][j] + bias[n0 + tx * 4 + j];
            if (GELU) v = 0.5f * v * (1.f + erff(v * 0.70710678118654752f));
            if (RES) v = res[(size_t)m * N + n0 + tx * 4 + j] + v * mk;
            (&o.x)[j] = v;
        }
        *(float4*)&C[(size_t)m * N + n0 + tx * 4] = o;
    }
}

// ---------------- RoPE in place on q and k ----------------
__global__ __launch_bounds__(256) void k_rope(
    float* __restrict__ q, float* __restrict__ k,
    const float* __restrict__ ct, const float* __restrict__ st) {
    int i = blockIdx.x * 256 + threadIdx.x;  // B*S*H*16 = 1048576
    int p = i & 15;
    int h = (i >> 4) & 7;
    int row = i >> 7;        // b*S+s
    int s = row & (SS - 1);
    float c = ct[s * 16 + p], sn = st[s * 16 + p];
    size_t base = (size_t)row * DD + h * HDIM;
    float q0 = q[base + p], q1 = q[base + 16 + p];
    q[base + p]      = q0 * c - q1 * sn;
    q[base + 16 + p] = q1 * c + q0 * sn;
    float k0 = k[base + p], k1 = k[base + 16 + p];
    k[base + p]      = k0 * c - k1 * sn;
    k[base + 16 + p] = k1 * c + k0 * sn;
}

// ---------------- attention scores: per (b,h), 64x64 tile, K=32 ----------------
// scores[z][q][k] = scale * dot(Q[b,q,h,:], K[b,k,h,:]),  z = local bh (bg group of 4 b's)
__global__ __launch_bounds__(256) void k_scores(
    const float* __restrict__ q, const float* __restrict__ k,
    float* __restrict__ sc, int bg) {
    __shared__ float Qt[32][68];   // [d][m]
    __shared__ float Kt[32][68];   // [d][n]
    int z = blockIdx.z;            // 0..31
    int b = bg * 4 + (z >> 3), h = z & 7;
    int q0 = blockIdx.x * 64, k0 = blockIdx.y * 64;
    int t = threadIdx.x;
    int rr = t >> 3;               // 0..31
    int dq = (t & 7) * 4;          // 0..28
#pragma unroll
    for (int i = 0; i < 2; ++i) {
        int row = rr + i * 32;
        float4 a = *(const float4*)&q[((size_t)(b * SS + q0 + row)) * DD + h * HDIM + dq];
        Qt[dq + 0][row] = a.x; Qt[dq + 1][row] = a.y; Qt[dq + 2][row] = a.z; Qt[dq + 3][row] = a.w;
        float4 w = *(const float4*)&k[((size_t)(b * SS + k0 + row)) * DD + h * HDIM + dq];
        Kt[dq + 0][row] = w.x; Kt[dq + 1][row] = w.y; Kt[dq + 2][row] = w.z; Kt[dq + 3][row] = w.w;
    }
    __syncthreads();
    int tx = t & 15, ty = t >> 4;
    float c[4][4] = {};
#pragma unroll
    for (int d = 0; d < 32; ++d) {
        float4 a4 = *(const float4*)&Qt[d][ty * 4];
        float4 b4 = *(const float4*)&Kt[d][tx * 4];
        const float aa[4] = {a4.x, a4.y, a4.z, a4.w};
        const float bb[4] = {b4.x, b4.y, b4.z, b4.w};
#pragma unroll
        for (int i = 0; i < 4; ++i)
#pragma unroll
            for (int j = 0; j < 4; ++j) c[i][j] += aa[i] * bb[j];
    }
    const float scale = 0.17677669529663687f;  // 1/sqrt(32)
#pragma unroll
    for (int i = 0; i < 4; ++i) {
        float4 o = {c[i][0] * scale, c[i][1] * scale, c[i][2] * scale, c[i][3] * scale};
        *(float4*)&sc[((size_t)z * SS + q0 + ty * 4 + i) * SS + k0 + tx * 4] = o;
    }
}

// ---------------- masked softmax over rows of 512, in place ----------------
__global__ __launch_bounds__(256) void k_softmax(
    float* __restrict__ sc, const int* __restrict__ mask, int bg) {
    int row = blockIdx.x;          // z*S + qrow
    int z = row >> 9;
    int b = bg * 4 + (z >> 3);
    int t = threadIdx.x;
    float* p = &sc[(size_t)row * SS];
    float v0 = (mask[b * SS + t]       != 0) ? p[t]       : -3.4e38f;
    float v1 = (mask[b * SS + t + 256] != 0) ? p[t + 256] : -3.4e38f;
    __shared__ float red[8];
    int wid = t >> 6, lane = t & 63;
    float mx = wave_max(fmaxf(v0, v1));
    if (lane == 0) red[wid] = mx;
    __syncthreads();
    mx = fmaxf(fmaxf(red[0], red[1]), fmaxf(red[2], red[3]));
    float e0 = expf(v0 - mx), e1 = expf(v1 - mx);
    float sm = wave_sum(e0 + e1);
    if (lane == 0) red[4 + wid] = sm;
    __syncthreads();
    float inv = 1.f / (red[4] + red[5] + red[6] + red[7]);
    p[t] = e0 * inv;
    p[t + 256] = e1 * inv;
}

// ---------------- PV: ctx[b,q,h*32+n] = sum_k P[q,k] * V[b,k,h*32+n] ----------------
__global__ __launch_bounds__(256) void k_pv(
    const float* __restrict__ sc, const float* __restrict__ v,
    float* __restrict__ ctx, int bg) {
    __shared__ float Pt[64][68];   // [k][m]
    __shared__ float Vs[64][36];   // [k][n]
    int z = blockIdx.z;
    int b = bg * 4 + (z >> 3), h = z & 7;
    int q0 = blockIdx.x * 64;
    int t = threadIdx.x;
    int tx = t & 7, ty = t >> 3;   // n-group 0..7, m-group 0..31
    float c[2][4] = {};
    for (int k0 = 0; k0 < SS; k0 += 64) {
        int rr = t >> 4;            // 0..15
        int kq = (t & 15) * 4;      // 0..60
#pragma unroll
        for (int i = 0; i < 4; ++i) {
            int m = rr + i * 16;
            float4 pv = *(const float4*)&sc[((size_t)z * SS + q0 + m) * SS + k0 + kq];
            Pt[kq + 0][m] = pv.x; Pt[kq + 1][m] = pv.y; Pt[kq + 2][m] = pv.z; Pt[kq + 3][m] = pv.w;
        }
        int kk = t >> 2;            // 0..63
        int nq = (t & 3) * 8;       // 0,8,16,24
        float4 a = *(const float4*)&v[((size_t)(b * SS + k0 + kk)) * DD + h * HDIM + nq];
        float4 bz = *(const float4*)&v[((size_t)(b * SS + k0 + kk)) * DD + h * HDIM + nq + 4];
        *(float4*)&Vs[kk][nq] = a;
        *(float4*)&Vs[kk][nq + 4] = bz;
        __syncthreads();
#pragma unroll
        for (int kx = 0; kx < 64; ++kx) {
            float2 a2 = *(const float2*)&Pt[kx][ty * 2];
            float4 b4 = *(const float4*)&Vs[kx][tx * 4];
            c[0][0] += a2.x * b4.x; c[0][1] += a2.x * b4.y; c[0][2] += a2.x * b4.z; c[0][3] += a2.x * b4.w;
            c[1][0] += a2.y * b4.x; c[1][1] += a2.y * b4.y; c[1][2] += a2.y * b4.z; c[1][3] += a2.y * b4.w;
        }
        __syncthreads();
    }
#pragma unroll
    for (int i = 0; i < 2; ++i) {
        int m = q0 + ty * 2 + i;
        float4 o = {c[i][0], c[i][1], c[i][2], c[i][3]};
        *(float4*)&ctx[((size_t)(b * SS) + m) * DD + h * HDIM + tx * 4] = o;
    }
}

// ---------------- head ----------------
__global__ __launch_bounds__(256) void k_head_init(const float* __restrict__ hb, float* __restrict__ out) {
    int i = blockIdx.x * 256 + threadIdx.x;   // 16384
    out[i] = hb[i & (NSOUT - 1)];
}

__global__ __launch_bounds__(256) void k_head(
    const float* __restrict__ x, const float* __restrict__ W, float* __restrict__ out) {
    int n = blockIdx.x * 256 + threadIdx.x;   // 0..1023
    int k0 = blockIdx.y * 1024;               // 128 chunks
    float acc[16] = {};
    for (int kk = 0; kk < 1024; kk += 8) {
#pragma unroll
        for (int u = 0; u < 8; ++u) {
            int k = k0 + kk + u;
            float w = W[(size_t)k * NSOUT + n];
#pragma unroll
            for (int b = 0; b < 16; ++b)
                acc[b] += x[(size_t)b * SD + k] * w;   // uniform index -> scalar loads
        }
    }
#pragma unroll
    for (int b = 0; b < 16; ++b)
        atomicAdd(&out[b * NSOUT + n], acc[b]);
}

extern "C" void kernel_launch(void* const* d_in, const int* in_sizes, int n_in,
                              void* d_out, int out_size, void* d_ws, size_t ws_size,
                              hipStream_t stream) {
    const float* values = (const float*)d_in[0];
    const float* dib    = (const float*)d_in[1];
    const float* gamma  = (const float*)d_in[2];
    const float* mtyp   = (const float*)d_in[3];
    const int*   mask   = (const int*)d_in[4];
    const float* in_w   = (const float*)d_in[5];
    const float* in_b   = (const float*)d_in[6];
    const float* ln1_s  = (const float*)d_in[7];
    const float* ln1_b  = (const float*)d_in[8];
    const float* qw     = (const float*)d_in[9];
    const float* qb     = (const float*)d_in[10];
    const float* kw     = (const float*)d_in[11];
    const float* kb     = (const float*)d_in[12];
    const float* vw     = (const float*)d_in[13];
    const float* vb     = (const float*)d_in[14];
    const float* ow     = (const float*)d_in[15];
    const float* ob     = (const float*)d_in[16];
    const float* ln2_s  = (const float*)d_in[17];
    const float* ln2_b  = (const float*)d_in[18];
    const float* ffw1   = (const float*)d_in[19];
    const float* ffb1   = (const float*)d_in[20];
    const float* ffw2   = (const float*)d_in[21];
    const float* ffb2   = (const float*)d_in[22];
    const float* fn_s   = (const float*)d_in[23];
    const float* fn_b   = (const float*)d_in[24];
    const float* head_w = (const float*)d_in[25];
    const float* head_b = (const float*)d_in[26];
    float* out = (float*)d_out;

    float* ws  = (float*)d_ws;
    float* x   = ws;                  // 2,097,152
    float* h   = x + 2097152;
    float* q   = h + 2097152;
    float* k   = q + 2097152;
    float* v   = k + 2097152;
    float* ctx = v + 2097152;
    float* ff1 = ctx + 2097152;       // 8,388,608
    float* ct  = ff1 + 8388608;       // 8,192
    float* st  = ct + 8192;           // 8,192
    float* sc  = st + 8192;           // 8,388,608 (scores for 4 b's at a time)

    k_rope_table<<<32, 256, 0, stream>>>(ct, st);
    k_input_proj<<<8192, 256, 0, stream>>>(values, dib, gamma, mtyp, in_w, in_b, x);

    for (int l = 0; l < NL; ++l) {
        k_layernorm<<<ROWS, 256, 0, stream>>>(x, h, ln1_s + l * DD, ln1_b + l * DD);
        dim3 g4(128, 4);
        k_gemm<false, false><<<g4, 256, 0, stream>>>(h, qw + (size_t)l * DD * DD, qb + l * DD, q,
                                                     ROWS, DD, DD, nullptr, nullptr);
        k_gemm<false, false><<<g4, 256, 0, stream>>>(h, kw + (size_t)l * DD * DD, kb + l * DD, k,
                                                     ROWS, DD, DD, nullptr, nullptr);
        k_gemm<false, false><<<g4, 256, 0, stream>>>(h, vw + (size_t)l * DD * DD, vb + l * DD, v,
                                                     ROWS, DD, DD, nullptr, nullptr);
        k_rope<<<4096, 256, 0, stream>>>(q, k, ct, st);
        for (int bg = 0; bg < 4; ++bg) {
            k_scores<<<dim3(8, 8, 32), 256, 0, stream>>>(q, k, sc, bg);
            k_softmax<<<16384, 256, 0, stream>>>(sc, mask, bg);
            k_pv<<<dim3(8, 1, 32), 256, 0, stream>>>(sc, v, ctx, bg);
        }
        k_gemm<false, true><<<g4, 256, 0, stream>>>(ctx, ow + (size_t)l * DD * DD, ob + l * DD, x,
                                                    ROWS, DD, DD, x, mask);
        k_layernorm<<<ROWS, 256, 0, stream>>>(x, h, ln2_s + l * DD, ln2_b + l * DD);
        k_gemm<true, false><<<dim3(128, 16), 256, 0, stream>>>(h, ffw1 + (size_t)l * DD * FFD, ffb1 + l * FFD,
                                                               ff1, ROWS, FFD, DD, nullptr, nullptr);
        k_gemm<false, true><<<g4, 256, 0, stream>>>(ff1, ffw2 + (size_t)l * FFD * DD, ffb2 + l * DD, x,
                                                    ROWS, DD, FFD, x, nullptr);
    }

    k_layernorm<<<ROWS, 256, 0, stream>>>(x, h, fn_s, fn_b);
    k_head_init<<<64, 256, 0, stream>>>(head_b, out);
    k_head<<<dim3(4, 128), 256, 0, stream>>>(h, head_w, out);
}

// Round 2
// 1051.705 us; speedup vs baseline: 1.1905x; 1.1905x over previous
//
#include <hip/hip_runtime.h>
#include <math.h>

#define BB 16
#define SS 512
#define DD 256
#define HH 8
#define HDIM 32
#define FFD 1024
#define NL 2
#define NSOUT 1024
#define SD (SS*DD)      // 131072
#define ROWS (BB*SS)    // 8192

#define HEAD_KC 256
#define HEAD_NCH 512    // SD / HEAD_KC

__device__ __forceinline__ float wave_sum(float v) {
#pragma unroll
    for (int off = 32; off > 0; off >>= 1) v += __shfl_xor(v, off);
    return v;
}
__device__ __forceinline__ float wave_max(float v) {
#pragma unroll
    for (int off = 32; off > 0; off >>= 1) v = fmaxf(v, __shfl_xor(v, off));
    return v;
}

// ---------------- RoPE tables: cos/sin [S][16] ----------------
__global__ __launch_bounds__(256) void k_rope_table(float* ct, float* st) {
    int i = blockIdx.x * 256 + threadIdx.x;   // 8192 = 512*16
    if (i >= SS * 16) return;
    int s = i >> 4, f = i & 15;
    float invf = powf(10000.f, -(float)f / 16.f);
    float ang = (float)s * invf;
    ct[i] = cosf(ang);
    st[i] = sinf(ang);
}

// ---------------- input features + projection ----------------
__global__ __launch_bounds__(256) void k_input_proj(
    const float* __restrict__ values, const float* __restrict__ dib,
    const float* __restrict__ gamma, const float* __restrict__ mtyp,
    const float* __restrict__ in_w, const float* __restrict__ in_b,
    float* __restrict__ x) {
    int i = blockIdx.x * 256 + threadIdx.x;   // ROWS*DD
    int row = i >> 8, d = i & 255;
    float v = values[row];
    float f0 = (v >= 0.f) ? 1.f : -1.f;
    float f1 = fabsf(v);
    float f2 = gamma[row];
    float f3 = dib[row];
    float f4 = mtyp[row] * 2.f - 1.f;
    x[i] = f0 * in_w[d] + f1 * in_w[DD + d] + f2 * in_w[2 * DD + d]
         + f3 * in_w[3 * DD + d] + f4 * in_w[4 * DD + d] + in_b[d];
}

// ---------------- layernorm over D=256, one block per row ----------------
__global__ __launch_bounds__(256) void k_layernorm(
    const float* __restrict__ in, float* __restrict__ out,
    const float* __restrict__ sc, const float* __restrict__ bi) {
    int row = blockIdx.x;
    int t = threadIdx.x;
    float v = in[(size_t)row * DD + t];
    __shared__ float red[8];
    int wid = t >> 6, lane = t & 63;
    float s = wave_sum(v);
    if (lane == 0) red[wid] = s;
    __syncthreads();
    float mean = (red[0] + red[1] + red[2] + red[3]) * (1.f / DD);
    float dv = v - mean;
    float s2 = wave_sum(dv * dv);
    if (lane == 0) red[4 + wid] = s2;
    __syncthreads();
    float var = (red[4] + red[5] + red[6] + red[7]) * (1.f / DD);
    out[(size_t)row * DD + t] = dv * rsqrtf(var + 1e-5f) * sc[t] + bi[t];
}

// ---------------- generic fp32 GEMM: C[M,N] = A[M,K]@W[K,N] + bias ----------------
template <bool GELU, bool RES>
__global__ __launch_bounds__(256) void k_gemm(
    const float* __restrict__ A, const float* __restrict__ W,
    const float* __restrict__ bias, float* __restrict__ C,
    int M, int N, int K,
    const float* __restrict__ res, const int* __restrict__ mask) {
    __shared__ float As[16][68];   // [k][m]
    __shared__ float Ws[16][68];   // [k][n]
    int t = threadIdx.x;
    int tx = t & 15, ty = t >> 4;
    int m0 = blockIdx.x * 64, n0 = blockIdx.y * 64;
    int lm = t >> 2;            // 0..63
    int lk = (t & 3) * 4;       // 0,4,8,12
    int wk = t >> 4;            // 0..15
    int wn = (t & 15) * 4;      // 0..60
    float c[4][4] = {};
    for (int k0 = 0; k0 < K; k0 += 16) {
        float4 av = *(const float4*)&A[(size_t)(m0 + lm) * K + k0 + lk];
        As[lk + 0][lm] = av.x; As[lk + 1][lm] = av.y;
        As[lk + 2][lm] = av.z; As[lk + 3][lm] = av.w;
        *(float4*)&Ws[wk][wn] = *(const float4*)&W[(size_t)(k0 + wk) * N + n0 + wn];
        __syncthreads();
#pragma unroll
        for (int kk = 0; kk < 16; ++kk) {
            float4 a4 = *(const float4*)&As[kk][ty * 4];
            float4 b4 = *(const float4*)&Ws[kk][tx * 4];
            const float aa[4] = {a4.x, a4.y, a4.z, a4.w};
            const float bb[4] = {b4.x, b4.y, b4.z, b4.w};
#pragma unroll
            for (int i = 0; i < 4; ++i)
#pragma unroll
                for (int j = 0; j < 4; ++j) c[i][j] += aa[i] * bb[j];
        }
        __syncthreads();
    }
#pragma unroll
    for (int i = 0; i < 4; ++i) {
        int m = m0 + ty * 4 + i;
        float mk = 1.f;
        if (RES && mask) mk = (mask[m] != 0) ? 1.f : 0.f;
        float4 o;
#pragma unroll
        for (int j = 0; j < 4; ++j) {
            float v = c[i][j] + bias[n0 + tx * 4 + j];
            if (GELU) v = 0.5f * v * (1.f + erff(v * 0.70710678118654752f));
            if (RES) v = res[(size_t)m * N + n0 + tx * 4 + j] + v * mk;
            (&o.x)[j] = v;
        }
        *(float4*)&C[(size_t)m * N + n0 + tx * 4] = o;
    }
}

// ---------------- RoPE in place on q and k ----------------
__global__ __launch_bounds__(256) void k_rope(
    float* __restrict__ q, float* __restrict__ k,
    const float* __restrict__ ct, const float* __restrict__ st) {
    int i = blockIdx.x * 256 + threadIdx.x;  // B*S*H*16 = 1048576
    int p = i & 15;
    int h = (i >> 4) & 7;
    int row = i >> 7;        // b*S+s
    int s = row & (SS - 1);
    float c = ct[s * 16 + p], sn = st[s * 16 + p];
    size_t base = (size_t)row * DD + h * HDIM;
    float q0 = q[base + p], q1 = q[base + 16 + p];
    q[base + p]      = q0 * c - q1 * sn;
    q[base + 16 + p] = q1 * c + q0 * sn;
    float k0 = k[base + p], k1 = k[base + 16 + p];
    k[base + p]      = k0 * c - k1 * sn;
    k[base + 16 + p] = k1 * c + k0 * sn;
}

// ---------------- attention scores ----------------
__global__ __launch_bounds__(256) void k_scores(
    const float* __restrict__ q, const float* __restrict__ k,
    float* __restrict__ sc, int bg) {
    __shared__ float Qt[32][68];   // [d][m]
    __shared__ float Kt[32][68];   // [d][n]
    int z = blockIdx.z;            // 0..31
    int b = bg * 4 + (z >> 3), h = z & 7;
    int q0 = blockIdx.x * 64, k0 = blockIdx.y * 64;
    int t = threadIdx.x;
    int rr = t >> 3;               // 0..31
    int dq = (t & 7) * 4;          // 0..28
#pragma unroll
    for (int i = 0; i < 2; ++i) {
        int row = rr + i * 32;
        float4 a = *(const float4*)&q[((size_t)(b * SS + q0 + row)) * DD + h * HDIM + dq];
        Qt[dq + 0][row] = a.x; Qt[dq + 1][row] = a.y; Qt[dq + 2][row] = a.z; Qt[dq + 3][row] = a.w;
        float4 w = *(const float4*)&k[((size_t)(b * SS + k0 + row)) * DD + h * HDIM + dq];
        Kt[dq + 0][row] = w.x; Kt[dq + 1][row] = w.y; Kt[dq + 2][row] = w.z; Kt[dq + 3][row] = w.w;
    }
    __syncthreads();
    int tx = t & 15, ty = t >> 4;
    float c[4][4] = {};
#pragma unroll
    for (int d = 0; d < 32; ++d) {
        float4 a4 = *(const float4*)&Qt[d][ty * 4];
        float4 b4 = *(const float4*)&Kt[d][tx * 4];
        const float aa[4] = {a4.x, a4.y, a4.z, a4.w};
        const float bb[4] = {b4.x, b4.y, b4.z, b4.w};
#pragma unroll
        for (int i = 0; i < 4; ++i)
#pragma unroll
            for (int j = 0; j < 4; ++j) c[i][j] += aa[i] * bb[j];
    }
    const float scale = 0.17677669529663687f;  // 1/sqrt(32)
#pragma unroll
    for (int i = 0; i < 4; ++i) {
        float4 o = {c[i][0] * scale, c[i][1] * scale, c[i][2] * scale, c[i][3] * scale};
        *(float4*)&sc[((size_t)z * SS + q0 + ty * 4 + i) * SS + k0 + tx * 4] = o;
    }
}

// ---------------- masked softmax over rows of 512, in place ----------------
__global__ __launch_bounds__(256) void k_softmax(
    float* __restrict__ sc, const int* __restrict__ mask, int bg) {
    int row = blockIdx.x;          // z*S + qrow
    int z = row >> 9;
    int b = bg * 4 + (z >> 3);
    int t = threadIdx.x;
    float* p = &sc[(size_t)row * SS];
    float v0 = (mask[b * SS + t]       != 0) ? p[t]       : -3.4e38f;
    float v1 = (mask[b * SS + t + 256] != 0) ? p[t + 256] : -3.4e38f;
    __shared__ float red[8];
    int wid = t >> 6, lane = t & 63;
    float mx = wave_max(fmaxf(v0, v1));
    if (lane == 0) red[wid] = mx;
    __syncthreads();
    mx = fmaxf(fmaxf(red[0], red[1]), fmaxf(red[2], red[3]));
    float e0 = expf(v0 - mx), e1 = expf(v1 - mx);
    float sm = wave_sum(e0 + e1);
    if (lane == 0) red[4 + wid] = sm;
    __syncthreads();
    float inv = 1.f / (red[4] + red[5] + red[6] + red[7]);
    p[t] = e0 * inv;
    p[t + 256] = e1 * inv;
}

// ---------------- PV ----------------
__global__ __launch_bounds__(256) void k_pv(
    const float* __restrict__ sc, const float* __restrict__ v,
    float* __restrict__ ctx, int bg) {
    __shared__ float Pt[64][68];   // [k][m]
    __shared__ float Vs[64][36];   // [k][n]
    int z = blockIdx.z;
    int b = bg * 4 + (z >> 3), h = z & 7;
    int q0 = blockIdx.x * 64;
    int t = threadIdx.x;
    int tx = t & 7, ty = t >> 3;   // n-group 0..7, m-group 0..31
    float c[2][4] = {};
    for (int k0 = 0; k0 < SS; k0 += 64) {
        int rr = t >> 4;            // 0..15
        int kq = (t & 15) * 4;      // 0..60
#pragma unroll
        for (int i = 0; i < 4; ++i) {
            int m = rr + i * 16;
            float4 pv = *(const float4*)&sc[((size_t)z * SS + q0 + m) * SS + k0 + kq];
            Pt[kq + 0][m] = pv.x; Pt[kq + 1][m] = pv.y; Pt[kq + 2][m] = pv.z; Pt[kq + 3][m] = pv.w;
        }
        int kk = t >> 2;            // 0..63
        int nq = (t & 3) * 8;       // 0,8,16,24
        float4 a = *(const float4*)&v[((size_t)(b * SS + k0 + kk)) * DD + h * HDIM + nq];
        float4 bz = *(const float4*)&v[((size_t)(b * SS + k0 + kk)) * DD + h * HDIM + nq + 4];
        *(float4*)&Vs[kk][nq] = a;
        *(float4*)&Vs[kk][nq + 4] = bz;
        __syncthreads();
#pragma unroll
        for (int kx = 0; kx < 64; ++kx) {
            float2 a2 = *(const float2*)&Pt[kx][ty * 2];
            float4 b4 = *(const float4*)&Vs[kx][tx * 4];
            c[0][0] += a2.x * b4.x; c[0][1] += a2.x * b4.y; c[0][2] += a2.x * b4.z; c[0][3] += a2.x * b4.w;
            c[1][0] += a2.y * b4.x; c[1][1] += a2.y * b4.y; c[1][2] += a2.y * b4.z; c[1][3] += a2.y * b4.w;
        }
        __syncthreads();
    }
#pragma unroll
    for (int i = 0; i < 2; ++i) {
        int m = q0 + ty * 2 + i;
        float4 o = {c[i][0], c[i][1], c[i][2], c[i][3]};
        *(float4*)&ctx[((size_t)(b * SS) + m) * DD + h * HDIM + tx * 4] = o;
    }
}

// ---------------- head: partial GEMV over k-chunks, float4 W loads ----------------
// part[c][b][n] = sum_{k in chunk c} x[b][k] * W[k][n]
__global__ __launch_bounds__(256) void k_head_part(
    const float* __restrict__ x, const float* __restrict__ W,
    float* __restrict__ part) {
    __shared__ float xs[16 * HEAD_KC];
    int c = blockIdx.x;            // 0..511
    int k0 = c * HEAD_KC;
    int t = threadIdx.x;
#pragma unroll
    for (int b = 0; b < 16; ++b)
        xs[b * HEAD_KC + t] = x[(size_t)b * SD + k0 + t];
    __syncthreads();
    int n4 = t * 4;                // 0..1020
    float acc[16][4] = {};
#pragma unroll 4
    for (int k = 0; k < HEAD_KC; ++k) {
        float4 w = *(const float4*)&W[(size_t)(k0 + k) * NSOUT + n4];
#pragma unroll
        for (int b = 0; b < 16; ++b) {
            float xv = xs[b * HEAD_KC + k];
            acc[b][0] += xv * w.x; acc[b][1] += xv * w.y;
            acc[b][2] += xv * w.z; acc[b][3] += xv * w.w;
        }
    }
#pragma unroll
    for (int b = 0; b < 16; ++b) {
        float4 o = {acc[b][0], acc[b][1], acc[b][2], acc[b][3]};
        *(float4*)&part[((size_t)c * 16 + b) * NSOUT + n4] = o;
    }
}

// out[b][n] = head_b[n] + sum_c part[c][b][n]
__global__ __launch_bounds__(256) void k_head_reduce(
    const float* __restrict__ part, const float* __restrict__ hb,
    float* __restrict__ out) {
    int i = (blockIdx.x * 256 + threadIdx.x) * 4;  // 0..16380, grid 16 blocks
    float4 s = {0.f, 0.f, 0.f, 0.f};
#pragma unroll 8
    for (int c = 0; c < HEAD_NCH; ++c) {
        float4 p = *(const float4*)&part[(size_t)c * (16 * NSOUT) + i];
        s.x += p.x; s.y += p.y; s.z += p.z; s.w += p.w;
    }
    int n = i & (NSOUT - 1);
    float4 b4 = *(const float4*)&hb[n];
    float4 o = {s.x + b4.x, s.y + b4.y, s.z + b4.z, s.w + b4.w};
    *(float4*)&out[i] = o;
}

extern "C" void kernel_launch(void* const* d_in, const int* in_sizes, int n_in,
                              void* d_out, int out_size, void* d_ws, size_t ws_size,
                              hipStream_t stream) {
    const float* values = (const float*)d_in[0];
    const float* dib    = (const float*)d_in[1];
    const float* gamma  = (const float*)d_in[2];
    const float* mtyp   = (const float*)d_in[3];
    const int*   mask   = (const int*)d_in[4];
    const float* in_w   = (const float*)d_in[5];
    const float* in_b   = (const float*)d_in[6];
    const float* ln1_s  = (const float*)d_in[7];
    const float* ln1_b  = (const float*)d_in[8];
    const float* qw     = (const float*)d_in[9];
    const float* qb     = (const float*)d_in[10];
    const float* kw     = (const float*)d_in[11];
    const float* kb     = (const float*)d_in[12];
    const float* vw     = (const float*)d_in[13];
    const float* vb     = (const float*)d_in[14];
    const float* ow     = (const float*)d_in[15];
    const float* ob     = (const float*)d_in[16];
    const float* ln2_s  = (const float*)d_in[17];
    const float* ln2_b  = (const float*)d_in[18];
    const float* ffw1   = (const float*)d_in[19];
    const float* ffb1   = (const float*)d_in[20];
    const float* ffw2   = (const float*)d_in[21];
    const float* ffb2   = (const float*)d_in[22];
    const float* fn_s   = (const float*)d_in[23];
    const float* fn_b   = (const float*)d_in[24];
    const float* head_w = (const float*)d_in[25];
    const float* head_b = (const float*)d_in[26];
    float* out = (float*)d_out;

    float* ws  = (float*)d_ws;
    float* x   = ws;                  // 2,097,152
    float* h   = x + 2097152;
    float* q   = h + 2097152;
    float* k   = q + 2097152;
    float* v   = k + 2097152;
    float* ctx = v + 2097152;
    float* ff1 = ctx + 2097152;       // 8,388,608
    float* ct  = ff1 + 8388608;       // 8,192
    float* st  = ct + 8192;           // 8,192
    float* sc  = st + 8192;           // 8,388,608 (scores; reused as head partials)

    k_rope_table<<<32, 256, 0, stream>>>(ct, st);
    k_input_proj<<<8192, 256, 0, stream>>>(values, dib, gamma, mtyp, in_w, in_b, x);

    for (int l = 0; l < NL; ++l) {
        k_layernorm<<<ROWS, 256, 0, stream>>>(x, h, ln1_s + l * DD, ln1_b + l * DD);
        dim3 g4(128, 4);
        k_gemm<false, false><<<g4, 256, 0, stream>>>(h, qw + (size_t)l * DD * DD, qb + l * DD, q,
                                                     ROWS, DD, DD, nullptr, nullptr);
        k_gemm<false, false><<<g4, 256, 0, stream>>>(h, kw + (size_t)l * DD * DD, kb + l * DD, k,
                                                     ROWS, DD, DD, nullptr, nullptr);
        k_gemm<false, false><<<g4, 256, 0, stream>>>(h, vw + (size_t)l * DD * DD, vb + l * DD, v,
                                                     ROWS, DD, DD, nullptr, nullptr);
        k_rope<<<4096, 256, 0, stream>>>(q, k, ct, st);
        for (int bg = 0; bg < 4; ++bg) {
            k_scores<<<dim3(8, 8, 32), 256, 0, stream>>>(q, k, sc, bg);
            k_softmax<<<16384, 256, 0, stream>>>(sc, mask, bg);
            k_pv<<<dim3(8, 1, 32), 256, 0, stream>>>(sc, v, ctx, bg);
        }
        k_gemm<false, true><<<g4, 256, 0, stream>>>(ctx, ow + (size_t)l * DD * DD, ob + l * DD, x,
                                                    ROWS, DD, DD, x, mask);
        k_layernorm<<<ROWS, 256, 0, stream>>>(x, h, ln2_s + l * DD, ln2_b + l * DD);
        k_gemm<true, false><<<dim3(128, 16), 256, 0, stream>>>(h, ffw1 + (size_t)l * DD * FFD, ffb1 + l * FFD,
                                                               ff1, ROWS, FFD, DD, nullptr, nullptr);
        k_gemm<false, true><<<g4, 256, 0, stream>>>(ff1, ffw2 + (size_t)l * FFD * DD, ffb2 + l * DD, x,
                                                    ROWS, DD, FFD, x, nullptr);
    }

    k_layernorm<<<ROWS, 256, 0, stream>>>(x, h, fn_s, fn_b);
    k_head_part<<<HEAD_NCH, 256, 0, stream>>>(h, head_w, sc);
    k_head_reduce<<<16, 256, 0, stream>>>(sc, head_b, out);
}

// Round 3
// 613.047 us; speedup vs baseline: 2.0424x; 1.7155x over previous
//
#include <hip/hip_runtime.h>
#include <math.h>

#define BB 16
#define SS 512
#define DD 256
#define HH 8
#define HDIM 32
#define FFD 1024
#define NL 2
#define NSOUT 1024
#define SD (SS*DD)      // 131072
#define ROWS (BB*SS)    // 8192

#define HEAD_KC 256
#define HEAD_NCH 512    // SD / HEAD_KC

typedef __attribute__((ext_vector_type(8))) short short8;
typedef __attribute__((ext_vector_type(4))) float f32x4;

__device__ __forceinline__ unsigned short f2bf(float f) {
    union { float f; unsigned u; } c; c.f = f;
    unsigned u = c.u + 0x7fffu + ((c.u >> 16) & 1u);
    return (unsigned short)(u >> 16);
}

__device__ __forceinline__ float wave_sum(float v) {
#pragma unroll
    for (int off = 32; off > 0; off >>= 1) v += __shfl_xor(v, off);
    return v;
}
__device__ __forceinline__ float wave_max(float v) {
#pragma unroll
    for (int off = 32; off > 0; off >>= 1) v = fmaxf(v, __shfl_xor(v, off));
    return v;
}

// ---------------- RoPE tables: cos/sin [S][16] ----------------
__global__ __launch_bounds__(256) void k_rope_table(float* ct, float* st) {
    int i = blockIdx.x * 256 + threadIdx.x;
    if (i >= SS * 16) return;
    int s = i >> 4, f = i & 15;
    float invf = powf(10000.f, -(float)f / 16.f);
    float ang = (float)s * invf;
    ct[i] = cosf(ang);
    st[i] = sinf(ang);
}

// ---------------- weight transpose + fp32->bf16: src[K][N] -> dst[N][K] ----------------
__global__ __launch_bounds__(256) void k_prep_t(
    const float* __restrict__ src, unsigned short* __restrict__ dst, int K, int N) {
    __shared__ float tile[32][33];
    size_t zo = (size_t)blockIdx.z * K * N;
    int k0 = blockIdx.x * 32, n0 = blockIdx.y * 32;
    int t = threadIdx.x;
    int r = t >> 3, c4 = (t & 7) * 4;
    float4 a = *(const float4*)&src[zo + (size_t)(k0 + r) * N + n0 + c4];
    tile[r][c4 + 0] = a.x; tile[r][c4 + 1] = a.y; tile[r][c4 + 2] = a.z; tile[r][c4 + 3] = a.w;
    __syncthreads();
    unsigned o0 = f2bf(tile[c4 + 0][r]), o1 = f2bf(tile[c4 + 1][r]);
    unsigned o2 = f2bf(tile[c4 + 2][r]), o3 = f2bf(tile[c4 + 3][r]);
    uint2 ud = { o0 | (o1 << 16), o2 | (o3 << 16) };
    *(uint2*)&dst[zo + (size_t)(n0 + r) * K + k0 + c4] = ud;
}

// ---------------- input features + projection (fp32 x) ----------------
__global__ __launch_bounds__(256) void k_input_proj(
    const float* __restrict__ values, const float* __restrict__ dib,
    const float* __restrict__ gamma, const float* __restrict__ mtyp,
    const float* __restrict__ in_w, const float* __restrict__ in_b,
    float* __restrict__ x) {
    int i = blockIdx.x * 256 + threadIdx.x;
    int row = i >> 8, d = i & 255;
    float v = values[row];
    float f0 = (v >= 0.f) ? 1.f : -1.f;
    float f1 = fabsf(v);
    float f2 = gamma[row];
    float f3 = dib[row];
    float f4 = mtyp[row] * 2.f - 1.f;
    x[i] = f0 * in_w[d] + f1 * in_w[DD + d] + f2 * in_w[2 * DD + d]
         + f3 * in_w[3 * DD + d] + f4 * in_w[4 * DD + d] + in_b[d];
}

// ---------------- layernorm over D=256; OBF selects bf16 or fp32 output ----------------
template <bool OBF>
__global__ __launch_bounds__(256) void k_layernorm(
    const float* __restrict__ in, void* __restrict__ outp,
    const float* __restrict__ sc, const float* __restrict__ bi) {
    int row = blockIdx.x;
    int t = threadIdx.x;
    float v = in[(size_t)row * DD + t];
    __shared__ float red[8];
    int wid = t >> 6, lane = t & 63;
    float s = wave_sum(v);
    if (lane == 0) red[wid] = s;
    __syncthreads();
    float mean = (red[0] + red[1] + red[2] + red[3]) * (1.f / DD);
    float dv = v - mean;
    float s2 = wave_sum(dv * dv);
    if (lane == 0) red[4 + wid] = s2;
    __syncthreads();
    float var = (red[4] + red[5] + red[6] + red[7]) * (1.f / DD);
    float o = dv * rsqrtf(var + 1e-5f) * sc[t] + bi[t];
    if (OBF) ((unsigned short*)outp)[(size_t)row * DD + t] = f2bf(o);
    else     ((float*)outp)[(size_t)row * DD + t] = o;
}

// ---------------- bf16 MFMA GEMM: C[M,N] = A[M,K] @ Bt[N,K]^T + bias ----------------
// EPI: 0 none, 1 exact GELU, 2 residual+row-mask into resx, 3 plain residual into resx
template <int EPI, bool OBF>
__global__ __launch_bounds__(256) void k_gemm_bf16(
    const short* __restrict__ A, const short* __restrict__ Bt,
    const float* __restrict__ bias, void* __restrict__ Cout,
    int M, int N, int K, const float* __restrict__ resx, const int* __restrict__ mask) {
    __shared__ __align__(16) short As[128 * 32];
    __shared__ __align__(16) short Bs[128 * 32];
    int t = threadIdx.x;
    int lane = t & 63, wid = t >> 6;
    int wr = wid >> 1, wc = wid & 1;
    int m0 = blockIdx.x * 128, n0 = blockIdx.y * 128;
    f32x4 acc[4][4] = {};
    int srow = t >> 2, sslot = t & 3;
    for (int k0 = 0; k0 < K; k0 += 32) {
#pragma unroll
        for (int p = 0; p < 2; ++p) {
            int row = srow + p * 64;
            int sw = sslot ^ ((row >> 1) & 3);
            *(float4*)&As[row * 32 + sw * 8] =
                *(const float4*)&A[(size_t)(m0 + row) * K + k0 + sslot * 8];
            *(float4*)&Bs[row * 32 + sw * 8] =
                *(const float4*)&Bt[(size_t)(n0 + row) * K + k0 + sslot * 8];
        }
        __syncthreads();
        short8 af[4], bfr[4];
#pragma unroll
        for (int mt = 0; mt < 4; ++mt) {
            int row = wr * 64 + mt * 16 + (lane & 15);
            int sl = (lane >> 4) ^ ((row >> 1) & 3);
            af[mt] = *(const short8*)&As[row * 32 + sl * 8];
        }
#pragma unroll
        for (int nt = 0; nt < 4; ++nt) {
            int row = wc * 64 + nt * 16 + (lane & 15);
            int sl = (lane >> 4) ^ ((row >> 1) & 3);
            bfr[nt] = *(const short8*)&Bs[row * 32 + sl * 8];
        }
#pragma unroll
        for (int mt = 0; mt < 4; ++mt)
#pragma unroll
            for (int nt = 0; nt < 4; ++nt)
                acc[mt][nt] = __builtin_amdgcn_mfma_f32_16x16x32_bf16(af[mt], bfr[nt], acc[mt][nt], 0, 0, 0);
        __syncthreads();
    }
#pragma unroll
    for (int mt = 0; mt < 4; ++mt) {
#pragma unroll
        for (int i = 0; i < 4; ++i) {
            int gm = m0 + wr * 64 + mt * 16 + (lane >> 4) * 4 + i;
            float mk = 1.f;
            if (EPI == 2) mk = (mask[gm] != 0) ? 1.f : 0.f;
#pragma unroll
            for (int nt = 0; nt < 4; ++nt) {
                int gn = n0 + wc * 64 + nt * 16 + (lane & 15);
                float v = acc[mt][nt][i] + bias[gn];
                if (EPI == 1) v = 0.5f * v * (1.f + erff(v * 0.70710678118654752f));
                if (EPI == 2 || EPI == 3) v = resx[(size_t)gm * N + gn] + v * mk;
                if (OBF) ((unsigned short*)Cout)[(size_t)gm * N + gn] = f2bf(v);
                else     ((float*)Cout)[(size_t)gm * N + gn] = v;
            }
        }
    }
}

// ---------------- RoPE on fp32 q,k -> bf16 qb,kb ----------------
__global__ __launch_bounds__(256) void k_rope_cvt(
    const float* __restrict__ q, const float* __restrict__ k,
    unsigned short* __restrict__ qb, unsigned short* __restrict__ kb,
    const float* __restrict__ ct, const float* __restrict__ st) {
    int i = blockIdx.x * 256 + threadIdx.x;  // B*S*H*16
    int p = i & 15;
    int h = (i >> 4) & 7;
    int row = i >> 7;
    int s = row & (SS - 1);
    float c = ct[s * 16 + p], sn = st[s * 16 + p];
    size_t base = (size_t)row * DD + h * HDIM;
    float q0 = q[base + p], q1 = q[base + 16 + p];
    qb[base + p]      = f2bf(q0 * c - q1 * sn);
    qb[base + 16 + p] = f2bf(q1 * c + q0 * sn);
    float k0 = k[base + p], k1 = k[base + 16 + p];
    kb[base + p]      = f2bf(k0 * c - k1 * sn);
    kb[base + 16 + p] = f2bf(k1 * c + k0 * sn);
}

// ---------------- V fp32 [b*S+s][D] -> bf16 vt[(b*8+h)*32+d][S] ----------------
__global__ __launch_bounds__(256) void k_vt(
    const float* __restrict__ v, unsigned short* __restrict__ vt) {
    __shared__ float tile[32][65];
    int bh = blockIdx.x;          // b*8+h
    int b = bh >> 3, h = bh & 7;
    int s0 = blockIdx.y * 64;
    int t = threadIdx.x;
    int r = t >> 2, c8 = (t & 3) * 8;
    const float* src = &v[((size_t)(b * SS) + s0 + r) * DD + h * HDIM + c8];
    float4 a0 = *(const float4*)&src[0];
    float4 a1 = *(const float4*)&src[4];
    tile[c8 + 0][r] = a0.x; tile[c8 + 1][r] = a0.y; tile[c8 + 2][r] = a0.z; tile[c8 + 3][r] = a0.w;
    tile[c8 + 4][r] = a1.x; tile[c8 + 5][r] = a1.y; tile[c8 + 6][r] = a1.z; tile[c8 + 7][r] = a1.w;
    __syncthreads();
    int d = t >> 3, s8 = (t & 7) * 8;
    unsigned p0 = f2bf(tile[d][s8 + 0]) | (f2bf(tile[d][s8 + 1]) << 16);
    unsigned p1 = f2bf(tile[d][s8 + 2]) | (f2bf(tile[d][s8 + 3]) << 16);
    unsigned p2 = f2bf(tile[d][s8 + 4]) | (f2bf(tile[d][s8 + 5]) << 16);
    unsigned p3 = f2bf(tile[d][s8 + 6]) | (f2bf(tile[d][s8 + 7]) << 16);
    uint4 u = { p0, p1, p2, p3 };
    *(uint4*)&vt[((size_t)bh * HDIM + d) * SS + s0 + s8] = u;
}

// ---------------- attention scores via MFMA, direct from global ----------------
__global__ __launch_bounds__(256) void k_scores_mfma(
    const short* __restrict__ qb, const short* __restrict__ kb,
    float* __restrict__ sc, int bg) {
    int t = threadIdx.x, lane = t & 63, wid = t >> 6;
    int wr = wid >> 1, wc = wid & 1;
    int z = blockIdx.z;                 // 0..63
    int b = bg * 8 + (z >> 3), h = z & 7;
    int q0 = blockIdx.x * 128 + wr * 64;
    int c0 = blockIdx.y * 128 + wc * 64;
    short8 af[4], bfr[4];
#pragma unroll
    for (int mt = 0; mt < 4; ++mt)
        af[mt] = *(const short8*)&qb[((size_t)(b * SS) + q0 + mt * 16 + (lane & 15)) * DD + h * HDIM + (lane >> 4) * 8];
#pragma unroll
    for (int nt = 0; nt < 4; ++nt)
        bfr[nt] = *(const short8*)&kb[((size_t)(b * SS) + c0 + nt * 16 + (lane & 15)) * DD + h * HDIM + (lane >> 4) * 8];
    const float scale = 0.17677669529663687f;  // 1/sqrt(32)
#pragma unroll
    for (int mt = 0; mt < 4; ++mt)
#pragma unroll
        for (int nt = 0; nt < 4; ++nt) {
            f32x4 acc = {};
            acc = __builtin_amdgcn_mfma_f32_16x16x32_bf16(af[mt], bfr[nt], acc, 0, 0, 0);
#pragma unroll
            for (int i = 0; i < 4; ++i)
                sc[((size_t)z * SS + q0 + mt * 16 + (lane >> 4) * 4 + i) * SS + c0 + nt * 16 + (lane & 15)] = acc[i] * scale;
        }
}

// ---------------- masked softmax rows of 512: fp32 sc -> bf16 pb ----------------
__global__ __launch_bounds__(256) void k_softmax(
    const float* __restrict__ sc, unsigned short* __restrict__ pb,
    const int* __restrict__ mask, int bg) {
    int row = blockIdx.x;          // z*S + qrow, z in 0..63
    int z = row >> 9;
    int b = bg * 8 + (z >> 3);
    int t = threadIdx.x;
    const float* p = &sc[(size_t)row * SS];
    float v0 = (mask[b * SS + t]       != 0) ? p[t]       : -3.4e38f;
    float v1 = (mask[b * SS + t + 256] != 0) ? p[t + 256] : -3.4e38f;
    __shared__ float red[8];
    int wid = t >> 6, lane = t & 63;
    float mx = wave_max(fmaxf(v0, v1));
    if (lane == 0) red[wid] = mx;
    __syncthreads();
    mx = fmaxf(fmaxf(red[0], red[1]), fmaxf(red[2], red[3]));
    float e0 = expf(v0 - mx), e1 = expf(v1 - mx);
    float sm = wave_sum(e0 + e1);
    if (lane == 0) red[4 + wid] = sm;
    __syncthreads();
    float inv = 1.f / (red[4] + red[5] + red[6] + red[7]);
    pb[(size_t)row * SS + t]       = f2bf(e0 * inv);
    pb[(size_t)row * SS + t + 256] = f2bf(e1 * inv);
}

// ---------------- PV via MFMA: ctx = P @ V, K=512 ----------------
__global__ __launch_bounds__(256) void k_pv_mfma(
    const short* __restrict__ pb, const short* __restrict__ vt,
    unsigned short* __restrict__ ctxb, int bg) {
    int t = threadIdx.x, lane = t & 63, wr = t >> 6;  // 4 waves, 32 q-rows each
    int z = blockIdx.y;
    int b = bg * 8 + (z >> 3), h = z & 7;
    int q0 = blockIdx.x * 128 + wr * 32;
    int bh = b * HH + h;
    f32x4 acc[2][2] = {};
    for (int ks = 0; ks < 16; ++ks) {
        short8 af[2], bfr[2];
#pragma unroll
        for (int mt = 0; mt < 2; ++mt)
            af[mt] = *(const short8*)&pb[((size_t)z * SS + q0 + mt * 16 + (lane & 15)) * SS + ks * 32 + (lane >> 4) * 8];
#pragma unroll
        for (int nt = 0; nt < 2; ++nt)
            bfr[nt] = *(const short8*)&vt[((size_t)bh * HDIM + nt * 16 + (lane & 15)) * SS + ks * 32 + (lane >> 4) * 8];
#pragma unroll
        for (int mt = 0; mt < 2; ++mt)
#pragma unroll
            for (int nt = 0; nt < 2; ++nt)
                acc[mt][nt] = __builtin_amdgcn_mfma_f32_16x16x32_bf16(af[mt], bfr[nt], acc[mt][nt], 0, 0, 0);
    }
#pragma unroll
    for (int mt = 0; mt < 2; ++mt)
#pragma unroll
        for (int nt = 0; nt < 2; ++nt)
#pragma unroll
            for (int i = 0; i < 4; ++i)
                ctxb[((size_t)(b * SS) + q0 + mt * 16 + (lane >> 4) * 4 + i) * DD + h * HDIM + nt * 16 + (lane & 15)] =
                    f2bf(acc[mt][nt][i]);
}

// ---------------- head: fp32 partial GEMV + reduce ----------------
__global__ __launch_bounds__(256) void k_head_part(
    const float* __restrict__ x, const float* __restrict__ W,
    float* __restrict__ part) {
    __shared__ float xs[16 * HEAD_KC];
    int c = blockIdx.x;
    int k0 = c * HEAD_KC;
    int t = threadIdx.x;
#pragma unroll
    for (int b = 0; b < 16; ++b)
        xs[b * HEAD_KC + t] = x[(size_t)b * SD + k0 + t];
    __syncthreads();
    int n4 = t * 4;
    float acc[16][4] = {};
#pragma unroll 4
    for (int k = 0; k < HEAD_KC; ++k) {
        float4 w = *(const float4*)&W[(size_t)(k0 + k) * NSOUT + n4];
#pragma unroll
        for (int b = 0; b < 16; ++b) {
            float xv = xs[b * HEAD_KC + k];
            acc[b][0] += xv * w.x; acc[b][1] += xv * w.y;
            acc[b][2] += xv * w.z; acc[b][3] += xv * w.w;
        }
    }
#pragma unroll
    for (int b = 0; b < 16; ++b) {
        float4 o = {acc[b][0], acc[b][1], acc[b][2], acc[b][3]};
        *(float4*)&part[((size_t)c * 16 + b) * NSOUT + n4] = o;
    }
}

__global__ __launch_bounds__(256) void k_head_reduce(
    const float* __restrict__ part, const float* __restrict__ hb,
    float* __restrict__ out) {
    int i = (blockIdx.x * 256 + threadIdx.x) * 4;
    float4 s = {0.f, 0.f, 0.f, 0.f};
#pragma unroll 8
    for (int c = 0; c < HEAD_NCH; ++c) {
        float4 p = *(const float4*)&part[(size_t)c * (16 * NSOUT) + i];
        s.x += p.x; s.y += p.y; s.z += p.z; s.w += p.w;
    }
    int n = i & (NSOUT - 1);
    float4 b4 = *(const float4*)&hb[n];
    float4 o = {s.x + b4.x, s.y + b4.y, s.z + b4.z, s.w + b4.w};
    *(float4*)&out[i] = o;
}

extern "C" void kernel_launch(void* const* d_in, const int* in_sizes, int n_in,
                              void* d_out, int out_size, void* d_ws, size_t ws_size,
                              hipStream_t stream) {
    const float* values = (const float*)d_in[0];
    const float* dib    = (const float*)d_in[1];
    const float* gamma  = (const float*)d_in[2];
    const float* mtyp   = (const float*)d_in[3];
    const int*   mask   = (const int*)d_in[4];
    const float* in_w   = (const float*)d_in[5];
    const float* in_b   = (const float*)d_in[6];
    const float* ln1_s  = (const float*)d_in[7];
    const float* ln1_b  = (const float*)d_in[8];
    const float* p_qw   = (const float*)d_in[9];
    const float* p_qb   = (const float*)d_in[10];
    const float* p_kw   = (const float*)d_in[11];
    const float* p_kb   = (const float*)d_in[12];
    const float* p_vw   = (const float*)d_in[13];
    const float* p_vb   = (const float*)d_in[14];
    const float* p_ow   = (const float*)d_in[15];
    const float* p_ob   = (const float*)d_in[16];
    const float* ln2_s  = (const float*)d_in[17];
    const float* ln2_b  = (const float*)d_in[18];
    const float* p_f1w  = (const float*)d_in[19];
    const float* p_f1b  = (const float*)d_in[20];
    const float* p_f2w  = (const float*)d_in[21];
    const float* p_f2b  = (const float*)d_in[22];
    const float* fn_s   = (const float*)d_in[23];
    const float* fn_b   = (const float*)d_in[24];
    const float* head_w = (const float*)d_in[25];
    const float* head_b = (const float*)d_in[26];
    float* out = (float*)d_out;

    const size_t MB = 1u << 20;
    char* w = (char*)d_ws;
    float* x    = (float*)(w + 0 * MB);            // 8 MB fp32 residual stream
    float* qf   = (float*)(w + 8 * MB);            // 8 MB (also final-LN fp32 out)
    float* kf   = (float*)(w + 16 * MB);
    float* vf   = (float*)(w + 24 * MB);
    unsigned short* h16  = (unsigned short*)(w + 32 * MB);  // 4 MB each
    unsigned short* q16  = (unsigned short*)(w + 36 * MB);
    unsigned short* k16  = (unsigned short*)(w + 40 * MB);
    unsigned short* vt16 = (unsigned short*)(w + 44 * MB);
    unsigned short* cx16 = (unsigned short*)(w + 48 * MB);
    unsigned short* f116 = (unsigned short*)(w + 52 * MB);  // 16 MB
    unsigned short* wq16 = (unsigned short*)(w + 68 * MB);  // 256 KB each (2 layers)
    unsigned short* wk16 = (unsigned short*)(w + 68 * MB + 256 * 1024);
    unsigned short* wv16 = (unsigned short*)(w + 68 * MB + 512 * 1024);
    unsigned short* wo16 = (unsigned short*)(w + 68 * MB + 768 * 1024);
    unsigned short* wf116 = (unsigned short*)(w + 69 * MB); // 1 MB
    unsigned short* wf216 = (unsigned short*)(w + 70 * MB); // 1 MB
    float* ct   = (float*)(w + 71 * MB);
    float* st   = (float*)(w + 71 * MB + 64 * 1024);
    float* sc   = (float*)(w + 72 * MB);           // 67 MB fp32 scores (also head partials)
    unsigned short* pb = (unsigned short*)(w + 140 * MB);   // 33.5 MB bf16 P

    k_rope_table<<<32, 256, 0, stream>>>(ct, st);
    k_prep_t<<<dim3(8, 8, NL), 256, 0, stream>>>(p_qw, wq16, DD, DD);
    k_prep_t<<<dim3(8, 8, NL), 256, 0, stream>>>(p_kw, wk16, DD, DD);
    k_prep_t<<<dim3(8, 8, NL), 256, 0, stream>>>(p_vw, wv16, DD, DD);
    k_prep_t<<<dim3(8, 8, NL), 256, 0, stream>>>(p_ow, wo16, DD, DD);
    k_prep_t<<<dim3(8, 32, NL), 256, 0, stream>>>(p_f1w, wf116, DD, FFD);
    k_prep_t<<<dim3(32, 8, NL), 256, 0, stream>>>(p_f2w, wf216, FFD, DD);
    k_input_proj<<<8192, 256, 0, stream>>>(values, dib, gamma, mtyp, in_w, in_b, x);

    for (int l = 0; l < NL; ++l) {
        k_layernorm<true><<<ROWS, 256, 0, stream>>>(x, h16, ln1_s + l * DD, ln1_b + l * DD);
        dim3 g2(64, 2);
        k_gemm_bf16<0, false><<<g2, 256, 0, stream>>>((const short*)h16, (const short*)(wq16 + l * 65536),
            p_qb + l * DD, qf, ROWS, DD, DD, nullptr, nullptr);
        k_gemm_bf16<0, false><<<g2, 256, 0, stream>>>((const short*)h16, (const short*)(wk16 + l * 65536),
            p_kb + l * DD, kf, ROWS, DD, DD, nullptr, nullptr);
        k_gemm_bf16<0, false><<<g2, 256, 0, stream>>>((const short*)h16, (const short*)(wv16 + l * 65536),
            p_vb + l * DD, vf, ROWS, DD, DD, nullptr, nullptr);
        k_rope_cvt<<<4096, 256, 0, stream>>>(qf, kf, q16, k16, ct, st);
        k_vt<<<dim3(BB * HH, 8), 256, 0, stream>>>(vf, vt16);
        for (int bg = 0; bg < 2; ++bg) {
            k_scores_mfma<<<dim3(4, 4, 64), 256, 0, stream>>>((const short*)q16, (const short*)k16, sc, bg);
            k_softmax<<<64 * SS, 256, 0, stream>>>(sc, pb, mask, bg);
            k_pv_mfma<<<dim3(4, 64), 256, 0, stream>>>((const short*)pb, (const short*)vt16, cx16, bg);
        }
        k_gemm_bf16<2, false><<<g2, 256, 0, stream>>>((const short*)cx16, (const short*)(wo16 + l * 65536),
            p_ob + l * DD, x, ROWS, DD, DD, x, mask);
        k_layernorm<true><<<ROWS, 256, 0, stream>>>(x, h16, ln2_s + l * DD, ln2_b + l * DD);
        k_gemm_bf16<1, true><<<dim3(64, 8), 256, 0, stream>>>((const short*)h16, (const short*)(wf116 + l * 262144),
            p_f1b + l * FFD, f116, ROWS, FFD, DD, nullptr, nullptr);
        k_gemm_bf16<3, false><<<g2, 256, 0, stream>>>((const short*)f116, (const short*)(wf216 + l * 262144),
            p_f2b + l * DD, x, ROWS, DD, FFD, x, nullptr);
    }

    k_layernorm<false><<<ROWS, 256, 0, stream>>>(x, qf, fn_s, fn_b);
    k_head_part<<<HEAD_NCH, 256, 0, stream>>>(qf, head_w, sc);
    k_head_reduce<<<16, 256, 0, stream>>>(sc, head_b, out);
}

// Round 4
// 436.842 us; speedup vs baseline: 2.8663x; 1.4034x over previous
//
#include <hip/hip_runtime.h>
#include <math.h>

#define BB 16
#define SS 512
#define DD 256
#define HH 8
#define HDIM 32
#define FFD 1024
#define NL 2
#define NSOUT 1024
#define SD (SS*DD)      // 131072
#define ROWS (BB*SS)    // 8192

#define HEAD_KC 256
#define HEAD_NCH 512    // SD / HEAD_KC

typedef __attribute__((ext_vector_type(8))) short short8;
typedef __attribute__((ext_vector_type(4))) float f32x4;

__device__ __forceinline__ unsigned short f2bf(float f) {
    union { float f; unsigned u; } c; c.f = f;
    unsigned u = c.u + 0x7fffu + ((c.u >> 16) & 1u);
    return (unsigned short)(u >> 16);
}

__device__ __forceinline__ float wave_sum(float v) {
#pragma unroll
    for (int off = 32; off > 0; off >>= 1) v += __shfl_xor(v, off);
    return v;
}
__device__ __forceinline__ float wave_max(float v) {
#pragma unroll
    for (int off = 32; off > 0; off >>= 1) v = fmaxf(v, __shfl_xor(v, off));
    return v;
}

// ---------------- RoPE tables: cos/sin [S][16] ----------------
__global__ __launch_bounds__(256) void k_rope_table(float* ct, float* st) {
    int i = blockIdx.x * 256 + threadIdx.x;
    if (i >= SS * 16) return;
    int s = i >> 4, f = i & 15;
    float invf = powf(10000.f, -(float)f / 16.f);
    float ang = (float)s * invf;
    ct[i] = cosf(ang);
    st[i] = sinf(ang);
}

// ---------------- weight transpose + fp32->bf16: src[K][N] -> dst[N][K] ----------------
__global__ __launch_bounds__(256) void k_prep_t(
    const float* __restrict__ src, unsigned short* __restrict__ dst, int K, int N) {
    __shared__ float tile[32][33];
    size_t zo = (size_t)blockIdx.z * K * N;
    int k0 = blockIdx.x * 32, n0 = blockIdx.y * 32;
    int t = threadIdx.x;
    int r = t >> 3, c4 = (t & 7) * 4;
    float4 a = *(const float4*)&src[zo + (size_t)(k0 + r) * N + n0 + c4];
    tile[r][c4 + 0] = a.x; tile[r][c4 + 1] = a.y; tile[r][c4 + 2] = a.z; tile[r][c4 + 3] = a.w;
    __syncthreads();
    unsigned o0 = f2bf(tile[c4 + 0][r]), o1 = f2bf(tile[c4 + 1][r]);
    unsigned o2 = f2bf(tile[c4 + 2][r]), o3 = f2bf(tile[c4 + 3][r]);
    uint2 ud = { o0 | (o1 << 16), o2 | (o3 << 16) };
    *(uint2*)&dst[zo + (size_t)(n0 + r) * K + k0 + c4] = ud;
}

// ---------------- input features + projection (fp32 x) ----------------
__global__ __launch_bounds__(256) void k_input_proj(
    const float* __restrict__ values, const float* __restrict__ dib,
    const float* __restrict__ gamma, const float* __restrict__ mtyp,
    const float* __restrict__ in_w, const float* __restrict__ in_b,
    float* __restrict__ x) {
    int i = blockIdx.x * 256 + threadIdx.x;
    int row = i >> 8, d = i & 255;
    float v = values[row];
    float f0 = (v >= 0.f) ? 1.f : -1.f;
    float f1 = fabsf(v);
    float f2 = gamma[row];
    float f3 = dib[row];
    float f4 = mtyp[row] * 2.f - 1.f;
    x[i] = f0 * in_w[d] + f1 * in_w[DD + d] + f2 * in_w[2 * DD + d]
         + f3 * in_w[3 * DD + d] + f4 * in_w[4 * DD + d] + in_b[d];
}

// ---------------- layernorm over D=256; OBF selects bf16 or fp32 output ----------------
template <bool OBF>
__global__ __launch_bounds__(256) void k_layernorm(
    const float* __restrict__ in, void* __restrict__ outp,
    const float* __restrict__ sc, const float* __restrict__ bi) {
    int row = blockIdx.x;
    int t = threadIdx.x;
    float v = in[(size_t)row * DD + t];
    __shared__ float red[8];
    int wid = t >> 6, lane = t & 63;
    float s = wave_sum(v);
    if (lane == 0) red[wid] = s;
    __syncthreads();
    float mean = (red[0] + red[1] + red[2] + red[3]) * (1.f / DD);
    float dv = v - mean;
    float s2 = wave_sum(dv * dv);
    if (lane == 0) red[4 + wid] = s2;
    __syncthreads();
    float var = (red[4] + red[5] + red[6] + red[7]) * (1.f / DD);
    float o = dv * rsqrtf(var + 1e-5f) * sc[t] + bi[t];
    if (OBF) ((unsigned short*)outp)[(size_t)row * DD + t] = f2bf(o);
    else     ((float*)outp)[(size_t)row * DD + t] = o;
}

// ---------------- bf16 MFMA GEMM: C[M,N] = A[M,K] @ Bt[N,K]^T + bias ----------------
// EPI: 0 none, 1 exact GELU, 2 residual+row-mask into resx, 3 plain residual into resx
template <int EPI, bool OBF>
__global__ __launch_bounds__(256) void k_gemm_bf16(
    const short* __restrict__ A, const short* __restrict__ Bt,
    const float* __restrict__ bias, void* __restrict__ Cout,
    int M, int N, int K, const float* __restrict__ resx, const int* __restrict__ mask) {
    __shared__ __align__(16) short As[128 * 32];
    __shared__ __align__(16) short Bs[128 * 32];
    int t = threadIdx.x;
    int lane = t & 63, wid = t >> 6;
    int wr = wid >> 1, wc = wid & 1;
    int m0 = blockIdx.x * 128, n0 = blockIdx.y * 128;
    f32x4 acc[4][4] = {};
    int srow = t >> 2, sslot = t & 3;
    for (int k0 = 0; k0 < K; k0 += 32) {
#pragma unroll
        for (int p = 0; p < 2; ++p) {
            int row = srow + p * 64;
            int sw = sslot ^ ((row >> 1) & 3);
            *(float4*)&As[row * 32 + sw * 8] =
                *(const float4*)&A[(size_t)(m0 + row) * K + k0 + sslot * 8];
            *(float4*)&Bs[row * 32 + sw * 8] =
                *(const float4*)&Bt[(size_t)(n0 + row) * K + k0 + sslot * 8];
        }
        __syncthreads();
        short8 af[4], bfr[4];
#pragma unroll
        for (int mt = 0; mt < 4; ++mt) {
            int row = wr * 64 + mt * 16 + (lane & 15);
            int sl = (lane >> 4) ^ ((row >> 1) & 3);
            af[mt] = *(const short8*)&As[row * 32 + sl * 8];
        }
#pragma unroll
        for (int nt = 0; nt < 4; ++nt) {
            int row = wc * 64 + nt * 16 + (lane & 15);
            int sl = (lane >> 4) ^ ((row >> 1) & 3);
            bfr[nt] = *(const short8*)&Bs[row * 32 + sl * 8];
        }
#pragma unroll
        for (int mt = 0; mt < 4; ++mt)
#pragma unroll
            for (int nt = 0; nt < 4; ++nt)
                acc[mt][nt] = __builtin_amdgcn_mfma_f32_16x16x32_bf16(af[mt], bfr[nt], acc[mt][nt], 0, 0, 0);
        __syncthreads();
    }
#pragma unroll
    for (int mt = 0; mt < 4; ++mt) {
#pragma unroll
        for (int i = 0; i < 4; ++i) {
            int gm = m0 + wr * 64 + mt * 16 + (lane >> 4) * 4 + i;
            float mk = 1.f;
            if (EPI == 2) mk = (mask[gm] != 0) ? 1.f : 0.f;
#pragma unroll
            for (int nt = 0; nt < 4; ++nt) {
                int gn = n0 + wc * 64 + nt * 16 + (lane & 15);
                float v = acc[mt][nt][i] + bias[gn];
                if (EPI == 1) v = 0.5f * v * (1.f + erff(v * 0.70710678118654752f));
                if (EPI == 2 || EPI == 3) v = resx[(size_t)gm * N + gn] + v * mk;
                if (OBF) ((unsigned short*)Cout)[(size_t)gm * N + gn] = f2bf(v);
                else     ((float*)Cout)[(size_t)gm * N + gn] = v;
            }
        }
    }
}

// ---------------- RoPE on fp32 q,k -> bf16 qb,kb ----------------
__global__ __launch_bounds__(256) void k_rope_cvt(
    const float* __restrict__ q, const float* __restrict__ k,
    unsigned short* __restrict__ qb, unsigned short* __restrict__ kb,
    const float* __restrict__ ct, const float* __restrict__ st) {
    int i = blockIdx.x * 256 + threadIdx.x;  // B*S*H*16
    int p = i & 15;
    int h = (i >> 4) & 7;
    int row = i >> 7;
    int s = row & (SS - 1);
    float c = ct[s * 16 + p], sn = st[s * 16 + p];
    size_t base = (size_t)row * DD + h * HDIM;
    float q0 = q[base + p], q1 = q[base + 16 + p];
    qb[base + p]      = f2bf(q0 * c - q1 * sn);
    qb[base + 16 + p] = f2bf(q1 * c + q0 * sn);
    float k0 = k[base + p], k1 = k[base + 16 + p];
    kb[base + p]      = f2bf(k0 * c - k1 * sn);
    kb[base + 16 + p] = f2bf(k1 * c + k0 * sn);
}

// ---------------- V fp32 [b*S+s][D] -> bf16 vt[(b*8+h)*32+d][S] ----------------
__global__ __launch_bounds__(256) void k_vt(
    const float* __restrict__ v, unsigned short* __restrict__ vt) {
    __shared__ float tile[32][65];
    int bh = blockIdx.x;          // b*8+h
    int b = bh >> 3, h = bh & 7;
    int s0 = blockIdx.y * 64;
    int t = threadIdx.x;
    int r = t >> 2, c8 = (t & 3) * 8;
    const float* src = &v[((size_t)(b * SS) + s0 + r) * DD + h * HDIM + c8];
    float4 a0 = *(const float4*)&src[0];
    float4 a1 = *(const float4*)&src[4];
    tile[c8 + 0][r] = a0.x; tile[c8 + 1][r] = a0.y; tile[c8 + 2][r] = a0.z; tile[c8 + 3][r] = a0.w;
    tile[c8 + 4][r] = a1.x; tile[c8 + 5][r] = a1.y; tile[c8 + 6][r] = a1.z; tile[c8 + 7][r] = a1.w;
    __syncthreads();
    int d = t >> 3, s8 = (t & 7) * 8;
    unsigned p0 = f2bf(tile[d][s8 + 0]) | (f2bf(tile[d][s8 + 1]) << 16);
    unsigned p1 = f2bf(tile[d][s8 + 2]) | (f2bf(tile[d][s8 + 3]) << 16);
    unsigned p2 = f2bf(tile[d][s8 + 4]) | (f2bf(tile[d][s8 + 5]) << 16);
    unsigned p3 = f2bf(tile[d][s8 + 6]) | (f2bf(tile[d][s8 + 7]) << 16);
    uint4 u = { p0, p1, p2, p3 };
    *(uint4*)&vt[((size_t)bh * HDIM + d) * SS + s0 + s8] = u;
}

// ---------------- fused flash attention: ctx = softmax(QK^T*scale + maskbias) @ V ----
// grid: (4 q-tiles, 128 bh); 4 independent waves per block, 32 q-rows each.
__global__ __launch_bounds__(256) void k_flash(
    const short* __restrict__ qb, const short* __restrict__ kb,
    const short* __restrict__ vt, const int* __restrict__ mask,
    unsigned short* __restrict__ ctxb) {
    __shared__ float bias_lds[SS];
    __shared__ __align__(16) short p_lds[4][32 * 72];
    __shared__ __align__(16) float r_lds[4][32];
    int t = threadIdx.x, lane = t & 63, wq = t >> 6;
    int bh = blockIdx.y;
    int b = bh >> 3, h = bh & 7;
    int q0 = blockIdx.x * 128 + wq * 32;
    bias_lds[t]       = (mask[b * SS + t]       != 0) ? 0.f : -3.0e38f;
    bias_lds[t + 256] = (mask[b * SS + t + 256] != 0) ? 0.f : -3.0e38f;
    __syncthreads();
    int l15 = lane & 15, lh = lane >> 4;
    short8 qfr[2];
    qfr[0] = *(const short8*)&qb[((size_t)(b * SS) + q0 + l15) * DD + h * HDIM + lh * 8];
    qfr[1] = *(const short8*)&qb[((size_t)(b * SS) + q0 + 16 + l15) * DD + h * HDIM + lh * 8];
    float m[2] = {-3.0e38f, -3.0e38f};
    float lsum[2] = {0.f, 0.f};
    f32x4 oacc[2][2] = {};   // [mf = q-frag][df = d-frag]
    const float scale = 0.17677669529663687f;  // 1/sqrt(32)
    for (int k0 = 0; k0 < SS; k0 += 64) {
        // swapped QK^T: A = K rows (k index), B = Q rows (q index)
        f32x4 sT[4][2];
#pragma unroll
        for (int kt = 0; kt < 4; ++kt) {
            short8 kf = *(const short8*)&kb[((size_t)(b * SS) + k0 + kt * 16 + l15) * DD + h * HDIM + lh * 8];
#pragma unroll
            for (int qf = 0; qf < 2; ++qf) {
                f32x4 z = {0.f, 0.f, 0.f, 0.f};
                sT[kt][qf] = __builtin_amdgcn_mfma_f32_16x16x32_bf16(kf, qfr[qf], z, 0, 0, 0);
            }
        }
        // online softmax per q-frag; thread owns q = qf*16 + l15, 16 k-values
        float p[2][16];
        float r[2];
#pragma unroll
        for (int qf = 0; qf < 2; ++qf) {
            float pmax = -3.0e38f;
#pragma unroll
            for (int kt = 0; kt < 4; ++kt)
#pragma unroll
                for (int i = 0; i < 4; ++i) {
                    float s = sT[kt][qf][i] * scale + bias_lds[k0 + kt * 16 + lh * 4 + i];
                    p[qf][kt * 4 + i] = s;
                    pmax = fmaxf(pmax, s);
                }
            pmax = fmaxf(pmax, __shfl_xor(pmax, 16));
            pmax = fmaxf(pmax, __shfl_xor(pmax, 32));
            float mn = fmaxf(m[qf], pmax);
            r[qf] = expf(m[qf] - mn);
            m[qf] = mn;
            float cs = 0.f;
#pragma unroll
            for (int j = 0; j < 16; ++j) {
                float e = expf(p[qf][j] - mn);
                p[qf][j] = e;
                cs += e;
            }
            cs += __shfl_xor(cs, 16);
            cs += __shfl_xor(cs, 32);
            lsum[qf] = lsum[qf] * r[qf] + cs;
        }
        // P -> per-wave LDS [q][72-padded k]
#pragma unroll
        for (int qf = 0; qf < 2; ++qf) {
            int qq = qf * 16 + l15;
#pragma unroll
            for (int kt = 0; kt < 4; ++kt) {
                unsigned u0 = (unsigned)f2bf(p[qf][kt * 4 + 0]) | ((unsigned)f2bf(p[qf][kt * 4 + 1]) << 16);
                unsigned u1 = (unsigned)f2bf(p[qf][kt * 4 + 2]) | ((unsigned)f2bf(p[qf][kt * 4 + 3]) << 16);
                uint2 u = { u0, u1 };
                *(uint2*)&p_lds[wq][qq * 72 + kt * 16 + lh * 4] = u;
            }
        }
        if (lane < 16) { r_lds[wq][l15] = r[0]; r_lds[wq][16 + l15] = r[1]; }
        __syncthreads();
        // rescale O by r (redistributed to PV layout: q = mf*16 + lh*4 + i)
#pragma unroll
        for (int mf = 0; mf < 2; ++mf) {
            float4 rv = *(const float4*)&r_lds[wq][mf * 16 + lh * 4];
#pragma unroll
            for (int df = 0; df < 2; ++df) {
                oacc[mf][df][0] *= rv.x; oacc[mf][df][1] *= rv.y;
                oacc[mf][df][2] *= rv.z; oacc[mf][df][3] *= rv.w;
            }
        }
        // PV: O += P @ V
#pragma unroll
        for (int ks = 0; ks < 2; ++ks) {
            short8 pa0 = *(const short8*)&p_lds[wq][(l15) * 72 + ks * 32 + lh * 8];
            short8 pa1 = *(const short8*)&p_lds[wq][(16 + l15) * 72 + ks * 32 + lh * 8];
#pragma unroll
            for (int df = 0; df < 2; ++df) {
                short8 vf = *(const short8*)&vt[((size_t)bh * HDIM + df * 16 + l15) * SS + k0 + ks * 32 + lh * 8];
                oacc[0][df] = __builtin_amdgcn_mfma_f32_16x16x32_bf16(pa0, vf, oacc[0][df], 0, 0, 0);
                oacc[1][df] = __builtin_amdgcn_mfma_f32_16x16x32_bf16(pa1, vf, oacc[1][df], 0, 0, 0);
            }
        }
        __syncthreads();
    }
    if (lane < 16) { r_lds[wq][l15] = 1.f / lsum[0]; r_lds[wq][16 + l15] = 1.f / lsum[1]; }
    __syncthreads();
#pragma unroll
    for (int mf = 0; mf < 2; ++mf) {
        float4 lv = *(const float4*)&r_lds[wq][mf * 16 + lh * 4];
        const float li[4] = { lv.x, lv.y, lv.z, lv.w };
#pragma unroll
        for (int df = 0; df < 2; ++df)
#pragma unroll
            for (int i = 0; i < 4; ++i) {
                int gq = q0 + mf * 16 + lh * 4 + i;
                int gd = df * 16 + l15;
                ctxb[((size_t)(b * SS) + gq) * DD + h * HDIM + gd] = f2bf(oacc[mf][df][i] * li[i]);
            }
    }
}

// ---------------- head: fp32 partial GEMV + reduce ----------------
__global__ __launch_bounds__(256) void k_head_part(
    const float* __restrict__ x, const float* __restrict__ W,
    float* __restrict__ part) {
    __shared__ float xs[16 * HEAD_KC];
    int c = blockIdx.x;
    int k0 = c * HEAD_KC;
    int t = threadIdx.x;
#pragma unroll
    for (int b = 0; b < 16; ++b)
        xs[b * HEAD_KC + t] = x[(size_t)b * SD + k0 + t];
    __syncthreads();
    int n4 = t * 4;
    float acc[16][4] = {};
#pragma unroll 4
    for (int k = 0; k < HEAD_KC; ++k) {
        float4 w = *(const float4*)&W[(size_t)(k0 + k) * NSOUT + n4];
#pragma unroll
        for (int b = 0; b < 16; ++b) {
            float xv = xs[b * HEAD_KC + k];
            acc[b][0] += xv * w.x; acc[b][1] += xv * w.y;
            acc[b][2] += xv * w.z; acc[b][3] += xv * w.w;
        }
    }
#pragma unroll
    for (int b = 0; b < 16; ++b) {
        float4 o = {acc[b][0], acc[b][1], acc[b][2], acc[b][3]};
        *(float4*)&part[((size_t)c * 16 + b) * NSOUT + n4] = o;
    }
}

__global__ __launch_bounds__(256) void k_head_reduce(
    const float* __restrict__ part, const float* __restrict__ hb,
    float* __restrict__ out) {
    int i = (blockIdx.x * 256 + threadIdx.x) * 4;
    float4 s = {0.f, 0.f, 0.f, 0.f};
#pragma unroll 8
    for (int c = 0; c < HEAD_NCH; ++c) {
        float4 p = *(const float4*)&part[(size_t)c * (16 * NSOUT) + i];
        s.x += p.x; s.y += p.y; s.z += p.z; s.w += p.w;
    }
    int n = i & (NSOUT - 1);
    float4 b4 = *(const float4*)&hb[n];
    float4 o = {s.x + b4.x, s.y + b4.y, s.z + b4.z, s.w + b4.w};
    *(float4*)&out[i] = o;
}

extern "C" void kernel_launch(void* const* d_in, const int* in_sizes, int n_in,
                              void* d_out, int out_size, void* d_ws, size_t ws_size,
                              hipStream_t stream) {
    const float* values = (const float*)d_in[0];
    const float* dib    = (const float*)d_in[1];
    const float* gamma  = (const float*)d_in[2];
    const float* mtyp   = (const float*)d_in[3];
    const int*   mask   = (const int*)d_in[4];
    const float* in_w   = (const float*)d_in[5];
    const float* in_b   = (const float*)d_in[6];
    const float* ln1_s  = (const float*)d_in[7];
    const float* ln1_b  = (const float*)d_in[8];
    const float* p_qw   = (const float*)d_in[9];
    const float* p_qb   = (const float*)d_in[10];
    const float* p_kw   = (const float*)d_in[11];
    const float* p_kb   = (const float*)d_in[12];
    const float* p_vw   = (const float*)d_in[13];
    const float* p_vb   = (const float*)d_in[14];
    const float* p_ow   = (const float*)d_in[15];
    const float* p_ob   = (const float*)d_in[16];
    const float* ln2_s  = (const float*)d_in[17];
    const float* ln2_b  = (const float*)d_in[18];
    const float* p_f1w  = (const float*)d_in[19];
    const float* p_f1b  = (const float*)d_in[20];
    const float* p_f2w  = (const float*)d_in[21];
    const float* p_f2b  = (const float*)d_in[22];
    const float* fn_s   = (const float*)d_in[23];
    const float* fn_b   = (const float*)d_in[24];
    const float* head_w = (const float*)d_in[25];
    const float* head_b = (const float*)d_in[26];
    float* out = (float*)d_out;

    const size_t MB = 1u << 20;
    char* w = (char*)d_ws;
    float* x    = (float*)(w + 0 * MB);            // 8 MB fp32 residual stream
    float* qf   = (float*)(w + 8 * MB);            // 8 MB (also final-LN fp32 out)
    float* kf   = (float*)(w + 16 * MB);
    float* vf   = (float*)(w + 24 * MB);
    unsigned short* h16  = (unsigned short*)(w + 32 * MB);  // 4 MB each
    unsigned short* q16  = (unsigned short*)(w + 36 * MB);
    unsigned short* k16  = (unsigned short*)(w + 40 * MB);
    unsigned short* vt16 = (unsigned short*)(w + 44 * MB);
    unsigned short* cx16 = (unsigned short*)(w + 48 * MB);
    unsigned short* f116 = (unsigned short*)(w + 52 * MB);  // 16 MB
    unsigned short* wq16 = (unsigned short*)(w + 68 * MB);  // 256 KB each (2 layers)
    unsigned short* wk16 = (unsigned short*)(w + 68 * MB + 256 * 1024);
    unsigned short* wv16 = (unsigned short*)(w + 68 * MB + 512 * 1024);
    unsigned short* wo16 = (unsigned short*)(w + 68 * MB + 768 * 1024);
    unsigned short* wf116 = (unsigned short*)(w + 69 * MB); // 1 MB
    unsigned short* wf216 = (unsigned short*)(w + 70 * MB); // 1 MB
    float* ct   = (float*)(w + 71 * MB);
    float* st   = (float*)(w + 71 * MB + 64 * 1024);
    float* sc   = (float*)(w + 72 * MB);           // head partials (33.5 MB)

    k_rope_table<<<32, 256, 0, stream>>>(ct, st);
    k_prep_t<<<dim3(8, 8, NL), 256, 0, stream>>>(p_qw, wq16, DD, DD);
    k_prep_t<<<dim3(8, 8, NL), 256, 0, stream>>>(p_kw, wk16, DD, DD);
    k_prep_t<<<dim3(8, 8, NL), 256, 0, stream>>>(p_vw, wv16, DD, DD);
    k_prep_t<<<dim3(8, 8, NL), 256, 0, stream>>>(p_ow, wo16, DD, DD);
    k_prep_t<<<dim3(8, 32, NL), 256, 0, stream>>>(p_f1w, wf116, DD, FFD);
    k_prep_t<<<dim3(32, 8, NL), 256, 0, stream>>>(p_f2w, wf216, FFD, DD);
    k_input_proj<<<8192, 256, 0, stream>>>(values, dib, gamma, mtyp, in_w, in_b, x);

    for (int l = 0; l < NL; ++l) {
        k_layernorm<true><<<ROWS, 256, 0, stream>>>(x, h16, ln1_s + l * DD, ln1_b + l * DD);
        dim3 g2(64, 2);
        k_gemm_bf16<0, false><<<g2, 256, 0, stream>>>((const short*)h16, (const short*)(wq16 + l * 65536),
            p_qb + l * DD, qf, ROWS, DD, DD, nullptr, nullptr);
        k_gemm_bf16<0, false><<<g2, 256, 0, stream>>>((const short*)h16, (const short*)(wk16 + l * 65536),
            p_kb + l * DD, kf, ROWS, DD, DD, nullptr, nullptr);
        k_gemm_bf16<0, false><<<g2, 256, 0, stream>>>((const short*)h16, (const short*)(wv16 + l * 65536),
            p_vb + l * DD, vf, ROWS, DD, DD, nullptr, nullptr);
        k_rope_cvt<<<4096, 256, 0, stream>>>(qf, kf, q16, k16, ct, st);
        k_vt<<<dim3(BB * HH, 8), 256, 0, stream>>>(vf, vt16);
        k_flash<<<dim3(4, BB * HH), 256, 0, stream>>>((const short*)q16, (const short*)k16,
            (const short*)vt16, mask, cx16);
        k_gemm_bf16<2, false><<<g2, 256, 0, stream>>>((const short*)cx16, (const short*)(wo16 + l * 65536),
            p_ob + l * DD, x, ROWS, DD, DD, x, mask);
        k_layernorm<true><<<ROWS, 256, 0, stream>>>(x, h16, ln2_s + l * DD, ln2_b + l * DD);
        k_gemm_bf16<1, true><<<dim3(64, 8), 256, 0, stream>>>((const short*)h16, (const short*)(wf116 + l * 262144),
            p_f1b + l * FFD, f116, ROWS, FFD, DD, nullptr, nullptr);
        k_gemm_bf16<3, false><<<g2, 256, 0, stream>>>((const short*)f116, (const short*)(wf216 + l * 262144),
            p_f2b + l * DD, x, ROWS, DD, FFD, x, nullptr);
    }

    k_layernorm<false><<<ROWS, 256, 0, stream>>>(x, qf, fn_s, fn_b);
    k_head_part<<<HEAD_NCH, 256, 0, stream>>>(qf, head_w, sc);
    k_head_reduce<<<16, 256, 0, stream>>>(sc, head_b, out);
}

// Round 5
// 371.077 us; speedup vs baseline: 3.3742x; 1.1772x over previous
//
#include <hip/hip_runtime.h>
#include <math.h>

#define BB 16
#define SS 512
#define DD 256
#define HH 8
#define HDIM 32
#define FFD 1024
#define NL 2
#define NSOUT 1024
#define SD (SS*DD)      // 131072
#define ROWS (BB*SS)    // 8192

#define HEAD_KC 256
#define HEAD_NCH 512    // SD / HEAD_KC

typedef __attribute__((ext_vector_type(8))) short short8;
typedef __attribute__((ext_vector_type(4))) float f32x4;

__device__ __forceinline__ unsigned short f2bf(float f) {
    union { float f; unsigned u; } c; c.f = f;
    unsigned u = c.u + 0x7fffu + ((c.u >> 16) & 1u);
    return (unsigned short)(u >> 16);
}

__device__ __forceinline__ float wave_sum(float v) {
#pragma unroll
    for (int off = 32; off > 0; off >>= 1) v += __shfl_xor(v, off);
    return v;
}
__device__ __forceinline__ float wave_max(float v) {
#pragma unroll
    for (int off = 32; off > 0; off >>= 1) v = fmaxf(v, __shfl_xor(v, off));
    return v;
}

// ---------------- RoPE tables: cos/sin [S][16] ----------------
__global__ __launch_bounds__(256) void k_rope_table(float* ct, float* st) {
    int i = blockIdx.x * 256 + threadIdx.x;
    if (i >= SS * 16) return;
    int s = i >> 4, f = i & 15;
    float invf = powf(10000.f, -(float)f / 16.f);
    float ang = (float)s * invf;
    ct[i] = cosf(ang);
    st[i] = sinf(ang);
}

// ---------------- weight transpose + fp32->bf16: src[K][N] -> dst[N][K] ----------------
__global__ __launch_bounds__(256) void k_prep_t(
    const float* __restrict__ src, unsigned short* __restrict__ dst, int K, int N) {
    __shared__ float tile[32][33];
    size_t zo = (size_t)blockIdx.z * K * N;
    int k0 = blockIdx.x * 32, n0 = blockIdx.y * 32;
    int t = threadIdx.x;
    int r = t >> 3, c4 = (t & 7) * 4;
    float4 a = *(const float4*)&src[zo + (size_t)(k0 + r) * N + n0 + c4];
    tile[r][c4 + 0] = a.x; tile[r][c4 + 1] = a.y; tile[r][c4 + 2] = a.z; tile[r][c4 + 3] = a.w;
    __syncthreads();
    unsigned o0 = f2bf(tile[c4 + 0][r]), o1 = f2bf(tile[c4 + 1][r]);
    unsigned o2 = f2bf(tile[c4 + 2][r]), o3 = f2bf(tile[c4 + 3][r]);
    uint2 ud = { o0 | (o1 << 16), o2 | (o3 << 16) };
    *(uint2*)&dst[zo + (size_t)(n0 + r) * K + k0 + c4] = ud;
}

// ---------------- input features + projection (fp32 x) ----------------
__global__ __launch_bounds__(256) void k_input_proj(
    const float* __restrict__ values, const float* __restrict__ dib,
    const float* __restrict__ gamma, const float* __restrict__ mtyp,
    const float* __restrict__ in_w, const float* __restrict__ in_b,
    float* __restrict__ x) {
    int i = blockIdx.x * 256 + threadIdx.x;
    int row = i >> 8, d = i & 255;
    float v = values[row];
    float f0 = (v >= 0.f) ? 1.f : -1.f;
    float f1 = fabsf(v);
    float f2 = gamma[row];
    float f3 = dib[row];
    float f4 = mtyp[row] * 2.f - 1.f;
    x[i] = f0 * in_w[d] + f1 * in_w[DD + d] + f2 * in_w[2 * DD + d]
         + f3 * in_w[3 * DD + d] + f4 * in_w[4 * DD + d] + in_b[d];
}

// ---------------- layernorm over D=256; OBF selects bf16 or fp32 output ----------------
template <bool OBF>
__global__ __launch_bounds__(256) void k_layernorm(
    const float* __restrict__ in, void* __restrict__ outp,
    const float* __restrict__ sc, const float* __restrict__ bi) {
    int row = blockIdx.x;
    int t = threadIdx.x;
    float v = in[(size_t)row * DD + t];
    __shared__ float red[8];
    int wid = t >> 6, lane = t & 63;
    float s = wave_sum(v);
    if (lane == 0) red[wid] = s;
    __syncthreads();
    float mean = (red[0] + red[1] + red[2] + red[3]) * (1.f / DD);
    float dv = v - mean;
    float s2 = wave_sum(dv * dv);
    if (lane == 0) red[4 + wid] = s2;
    __syncthreads();
    float var = (red[4] + red[5] + red[6] + red[7]) * (1.f / DD);
    float o = dv * rsqrtf(var + 1e-5f) * sc[t] + bi[t];
    if (OBF) ((unsigned short*)outp)[(size_t)row * DD + t] = f2bf(o);
    else     ((float*)outp)[(size_t)row * DD + t] = o;
}

// ---------------- bf16 MFMA GEMM 128x128: C[M,N] = A[M,K] @ Bt[N,K]^T + bias --------
// EPI: 0 none, 1 exact GELU, 2 residual+row-mask into resx, 3 plain residual into resx
template <int EPI, bool OBF>
__global__ __launch_bounds__(256) void k_gemm_bf16(
    const short* __restrict__ A, const short* __restrict__ Bt,
    const float* __restrict__ bias, void* __restrict__ Cout,
    int M, int N, int K, const float* __restrict__ resx, const int* __restrict__ mask) {
    __shared__ __align__(16) short As[128 * 32];
    __shared__ __align__(16) short Bs[128 * 32];
    int t = threadIdx.x;
    int lane = t & 63, wid = t >> 6;
    int wr = wid >> 1, wc = wid & 1;
    int m0 = blockIdx.x * 128, n0 = blockIdx.y * 128;
    f32x4 acc[4][4] = {};
    int srow = t >> 2, sslot = t & 3;
    for (int k0 = 0; k0 < K; k0 += 32) {
#pragma unroll
        for (int p = 0; p < 2; ++p) {
            int row = srow + p * 64;
            int sw = sslot ^ ((row >> 1) & 3);
            *(float4*)&As[row * 32 + sw * 8] =
                *(const float4*)&A[(size_t)(m0 + row) * K + k0 + sslot * 8];
            *(float4*)&Bs[row * 32 + sw * 8] =
                *(const float4*)&Bt[(size_t)(n0 + row) * K + k0 + sslot * 8];
        }
        __syncthreads();
        short8 af[4], bfr[4];
#pragma unroll
        for (int mt = 0; mt < 4; ++mt) {
            int row = wr * 64 + mt * 16 + (lane & 15);
            int sl = (lane >> 4) ^ ((row >> 1) & 3);
            af[mt] = *(const short8*)&As[row * 32 + sl * 8];
        }
#pragma unroll
        for (int nt = 0; nt < 4; ++nt) {
            int row = wc * 64 + nt * 16 + (lane & 15);
            int sl = (lane >> 4) ^ ((row >> 1) & 3);
            bfr[nt] = *(const short8*)&Bs[row * 32 + sl * 8];
        }
#pragma unroll
        for (int mt = 0; mt < 4; ++mt)
#pragma unroll
            for (int nt = 0; nt < 4; ++nt)
                acc[mt][nt] = __builtin_amdgcn_mfma_f32_16x16x32_bf16(af[mt], bfr[nt], acc[mt][nt], 0, 0, 0);
        __syncthreads();
    }
#pragma unroll
    for (int mt = 0; mt < 4; ++mt) {
#pragma unroll
        for (int i = 0; i < 4; ++i) {
            int gm = m0 + wr * 64 + mt * 16 + (lane >> 4) * 4 + i;
            float mk = 1.f;
            if (EPI == 2) mk = (mask[gm] != 0) ? 1.f : 0.f;
#pragma unroll
            for (int nt = 0; nt < 4; ++nt) {
                int gn = n0 + wc * 64 + nt * 16 + (lane & 15);
                float v = acc[mt][nt][i] + bias[gn];
                if (EPI == 1) v = 0.5f * v * (1.f + erff(v * 0.70710678118654752f));
                if (EPI == 2 || EPI == 3) v = resx[(size_t)gm * N + gn] + v * mk;
                if (OBF) ((unsigned short*)Cout)[(size_t)gm * N + gn] = f2bf(v);
                else     ((float*)Cout)[(size_t)gm * N + gn] = v;
            }
        }
    }
}

// ---------------- bf16 MFMA GEMM 64x128 (full-GPU grids for N=256 outputs) ----------
// EPI: 2 residual+row-mask into resx, 3 plain residual. fp32 output.
template <int EPI>
__global__ __launch_bounds__(256) void k_gemm64(
    const short* __restrict__ A, const short* __restrict__ Bt,
    const float* __restrict__ bias, float* __restrict__ Cout,
    int M, int N, int K, const float* __restrict__ resx, const int* __restrict__ mask) {
    __shared__ __align__(16) short As[64 * 32];
    __shared__ __align__(16) short Bs[128 * 32];
    int t = threadIdx.x;
    int lane = t & 63, wid = t >> 6;
    int wr = wid >> 1, wc = wid & 1;          // wave: 32 rows x 64 cols
    int m0 = blockIdx.x * 64, n0 = blockIdx.y * 128;
    f32x4 acc[2][4] = {};
    int srow = t >> 2, sslot = t & 3;
    int l15 = lane & 15, lh = lane >> 4;
    for (int k0 = 0; k0 < K; k0 += 32) {
        {
            int sw = sslot ^ ((srow >> 1) & 3);
            *(float4*)&As[srow * 32 + sw * 8] =
                *(const float4*)&A[(size_t)(m0 + srow) * K + k0 + sslot * 8];
        }
#pragma unroll
        for (int p = 0; p < 2; ++p) {
            int row = srow + p * 64;
            int sw = sslot ^ ((row >> 1) & 3);
            *(float4*)&Bs[row * 32 + sw * 8] =
                *(const float4*)&Bt[(size_t)(n0 + row) * K + k0 + sslot * 8];
        }
        __syncthreads();
        short8 af[2], bfr[4];
#pragma unroll
        for (int mt = 0; mt < 2; ++mt) {
            int row = wr * 32 + mt * 16 + l15;
            int sl = lh ^ ((row >> 1) & 3);
            af[mt] = *(const short8*)&As[row * 32 + sl * 8];
        }
#pragma unroll
        for (int nt = 0; nt < 4; ++nt) {
            int row = wc * 64 + nt * 16 + l15;
            int sl = lh ^ ((row >> 1) & 3);
            bfr[nt] = *(const short8*)&Bs[row * 32 + sl * 8];
        }
#pragma unroll
        for (int mt = 0; mt < 2; ++mt)
#pragma unroll
            for (int nt = 0; nt < 4; ++nt)
                acc[mt][nt] = __builtin_amdgcn_mfma_f32_16x16x32_bf16(af[mt], bfr[nt], acc[mt][nt], 0, 0, 0);
        __syncthreads();
    }
#pragma unroll
    for (int mt = 0; mt < 2; ++mt) {
#pragma unroll
        for (int i = 0; i < 4; ++i) {
            int gm = m0 + wr * 32 + mt * 16 + lh * 4 + i;
            float mk = 1.f;
            if (EPI == 2) mk = (mask[gm] != 0) ? 1.f : 0.f;
#pragma unroll
            for (int nt = 0; nt < 4; ++nt) {
                int gn = n0 + wc * 64 + nt * 16 + l15;
                float v = acc[mt][nt][i] + bias[gn];
                v = resx[(size_t)gm * N + gn] + v * mk;
                Cout[(size_t)gm * N + gn] = v;
            }
        }
    }
}

// ---------------- fused QKV GEMM + bias + RoPE / V-transpose epilogue ----------------
// grid (M/128, 6): blockIdx.y>>1 selects Q/K/V, &1 selects col half.
__global__ __launch_bounds__(256) void k_qkv(
    const short* __restrict__ A,
    const short* __restrict__ Wq, const short* __restrict__ Wk, const short* __restrict__ Wv,
    const float* __restrict__ bq, const float* __restrict__ bk, const float* __restrict__ bv,
    const float* __restrict__ ct, const float* __restrict__ st,
    unsigned short* __restrict__ q16, unsigned short* __restrict__ k16,
    unsigned short* __restrict__ vt16) {
    __shared__ __align__(16) short As[128 * 32];
    __shared__ __align__(16) short Bs[128 * 32];
    int mat = blockIdx.y >> 1;
    int n0 = (blockIdx.y & 1) * 128;
    const short* Bt = (mat == 0) ? Wq : (mat == 1) ? Wk : Wv;
    const float* bias = (mat == 0) ? bq : (mat == 1) ? bk : bv;
    int t = threadIdx.x;
    int lane = t & 63, wid = t >> 6;
    int wr = wid >> 1, wc = wid & 1;
    int m0 = blockIdx.x * 128;
    int l15 = lane & 15, lh = lane >> 4;
    f32x4 acc[4][4] = {};
    int srow = t >> 2, sslot = t & 3;
    for (int k0 = 0; k0 < DD; k0 += 32) {
#pragma unroll
        for (int p = 0; p < 2; ++p) {
            int row = srow + p * 64;
            int sw = sslot ^ ((row >> 1) & 3);
            *(float4*)&As[row * 32 + sw * 8] =
                *(const float4*)&A[(size_t)(m0 + row) * DD + k0 + sslot * 8];
            *(float4*)&Bs[row * 32 + sw * 8] =
                *(const float4*)&Bt[(size_t)(n0 + row) * DD + k0 + sslot * 8];
        }
        __syncthreads();
        short8 af[4], bfr[4];
#pragma unroll
        for (int mt = 0; mt < 4; ++mt) {
            int row = wr * 64 + mt * 16 + l15;
            int sl = lh ^ ((row >> 1) & 3);
            af[mt] = *(const short8*)&As[row * 32 + sl * 8];
        }
#pragma unroll
        for (int nt = 0; nt < 4; ++nt) {
            int row = wc * 64 + nt * 16 + l15;
            int sl = lh ^ ((row >> 1) & 3);
            bfr[nt] = *(const short8*)&Bs[row * 32 + sl * 8];
        }
#pragma unroll
        for (int mt = 0; mt < 4; ++mt)
#pragma unroll
            for (int nt = 0; nt < 4; ++nt)
                acc[mt][nt] = __builtin_amdgcn_mfma_f32_16x16x32_bf16(af[mt], bfr[nt], acc[mt][nt], 0, 0, 0);
        __syncthreads();
    }
    float bs[4];
#pragma unroll
    for (int nt = 0; nt < 4; ++nt) bs[nt] = bias[n0 + wc * 64 + nt * 16 + l15];
    if (mat < 2) {
        unsigned short* dst = (mat == 0) ? q16 : k16;
#pragma unroll
        for (int mt = 0; mt < 4; ++mt) {
#pragma unroll
            for (int i = 0; i < 4; ++i) {
                int gm = m0 + wr * 64 + mt * 16 + lh * 4 + i;
                int s = gm & (SS - 1);
                float c = ct[s * 16 + l15], sn = st[s * 16 + l15];
                float val[4];
#pragma unroll
                for (int nt = 0; nt < 4; ++nt) val[nt] = acc[mt][nt][i] + bs[nt];
#pragma unroll
                for (int nt = 0; nt < 4; ++nt) {
                    float partner = val[nt ^ 1];
                    float o = ((nt & 1) == 0) ? (val[nt] * c - partner * sn)
                                              : (val[nt] * c + partner * sn);
                    dst[(size_t)gm * DD + n0 + wc * 64 + nt * 16 + l15] = f2bf(o);
                }
            }
        }
    } else {
#pragma unroll
        for (int mt = 0; mt < 4; ++mt) {
            int gmb = m0 + wr * 64 + mt * 16 + lh * 4;
            int b = gmb >> 9, sb = gmb & (SS - 1);
#pragma unroll
            for (int nt = 0; nt < 4; ++nt) {
                int gn = n0 + wc * 64 + nt * 16 + l15;
                int h = gn >> 5, d = gn & 31;
                ushort4 u;
#pragma unroll
                for (int i = 0; i < 4; ++i)
                    (&u.x)[i] = f2bf(acc[mt][nt][i] + bs[nt]);
                *(ushort4*)&vt16[((size_t)((b * HH + h) * HDIM + d)) * SS + sb] = u;
            }
        }
    }
}

// ---------------- fused flash attention: ctx = softmax(QK^T*scale + maskbias) @ V ----
__global__ __launch_bounds__(256) void k_flash(
    const short* __restrict__ qb, const short* __restrict__ kb,
    const short* __restrict__ vt, const int* __restrict__ mask,
    unsigned short* __restrict__ ctxb) {
    __shared__ float bias_lds[SS];
    __shared__ __align__(16) short p_lds[4][32 * 72];
    __shared__ __align__(16) float r_lds[4][32];
    int t = threadIdx.x, lane = t & 63, wq = t >> 6;
    int bh = blockIdx.y;
    int b = bh >> 3, h = bh & 7;
    int q0 = blockIdx.x * 128 + wq * 32;
    bias_lds[t]       = (mask[b * SS + t]       != 0) ? 0.f : -3.0e38f;
    bias_lds[t + 256] = (mask[b * SS + t + 256] != 0) ? 0.f : -3.0e38f;
    __syncthreads();
    int l15 = lane & 15, lh = lane >> 4;
    short8 qfr[2];
    qfr[0] = *(const short8*)&qb[((size_t)(b * SS) + q0 + l15) * DD + h * HDIM + lh * 8];
    qfr[1] = *(const short8*)&qb[((size_t)(b * SS) + q0 + 16 + l15) * DD + h * HDIM + lh * 8];
    float m[2] = {-3.0e38f, -3.0e38f};
    float lsum[2] = {0.f, 0.f};
    f32x4 oacc[2][2] = {};   // [mf = q-frag][df = d-frag]
    const float scale = 0.17677669529663687f;  // 1/sqrt(32)
    for (int k0 = 0; k0 < SS; k0 += 64) {
        f32x4 sT[4][2];
#pragma unroll
        for (int kt = 0; kt < 4; ++kt) {
            short8 kf = *(const short8*)&kb[((size_t)(b * SS) + k0 + kt * 16 + l15) * DD + h * HDIM + lh * 8];
#pragma unroll
            for (int qf = 0; qf < 2; ++qf) {
                f32x4 z = {0.f, 0.f, 0.f, 0.f};
                sT[kt][qf] = __builtin_amdgcn_mfma_f32_16x16x32_bf16(kf, qfr[qf], z, 0, 0, 0);
            }
        }
        float p[2][16];
        float r[2];
#pragma unroll
        for (int qf = 0; qf < 2; ++qf) {
            float pmax = -3.0e38f;
#pragma unroll
            for (int kt = 0; kt < 4; ++kt)
#pragma unroll
                for (int i = 0; i < 4; ++i) {
                    float s = sT[kt][qf][i] * scale + bias_lds[k0 + kt * 16 + lh * 4 + i];
                    p[qf][kt * 4 + i] = s;
                    pmax = fmaxf(pmax, s);
                }
            pmax = fmaxf(pmax, __shfl_xor(pmax, 16));
            pmax = fmaxf(pmax, __shfl_xor(pmax, 32));
            float mn = fmaxf(m[qf], pmax);
            r[qf] = expf(m[qf] - mn);
            m[qf] = mn;
            float cs = 0.f;
#pragma unroll
            for (int j = 0; j < 16; ++j) {
                float e = expf(p[qf][j] - mn);
                p[qf][j] = e;
                cs += e;
            }
            cs += __shfl_xor(cs, 16);
            cs += __shfl_xor(cs, 32);
            lsum[qf] = lsum[qf] * r[qf] + cs;
        }
#pragma unroll
        for (int qf = 0; qf < 2; ++qf) {
            int qq = qf * 16 + l15;
#pragma unroll
            for (int kt = 0; kt < 4; ++kt) {
                unsigned u0 = (unsigned)f2bf(p[qf][kt * 4 + 0]) | ((unsigned)f2bf(p[qf][kt * 4 + 1]) << 16);
                unsigned u1 = (unsigned)f2bf(p[qf][kt * 4 + 2]) | ((unsigned)f2bf(p[qf][kt * 4 + 3]) << 16);
                uint2 u = { u0, u1 };
                *(uint2*)&p_lds[wq][qq * 72 + kt * 16 + lh * 4] = u;
            }
        }
        if (lane < 16) { r_lds[wq][l15] = r[0]; r_lds[wq][16 + l15] = r[1]; }
        __syncthreads();
#pragma unroll
        for (int mf = 0; mf < 2; ++mf) {
            float4 rv = *(const float4*)&r_lds[wq][mf * 16 + lh * 4];
#pragma unroll
            for (int df = 0; df < 2; ++df) {
                oacc[mf][df][0] *= rv.x; oacc[mf][df][1] *= rv.y;
                oacc[mf][df][2] *= rv.z; oacc[mf][df][3] *= rv.w;
            }
        }
#pragma unroll
        for (int ks = 0; ks < 2; ++ks) {
            short8 pa0 = *(const short8*)&p_lds[wq][(l15) * 72 + ks * 32 + lh * 8];
            short8 pa1 = *(const short8*)&p_lds[wq][(16 + l15) * 72 + ks * 32 + lh * 8];
#pragma unroll
            for (int df = 0; df < 2; ++df) {
                short8 vf = *(const short8*)&vt[((size_t)bh * HDIM + df * 16 + l15) * SS + k0 + ks * 32 + lh * 8];
                oacc[0][df] = __builtin_amdgcn_mfma_f32_16x16x32_bf16(pa0, vf, oacc[0][df], 0, 0, 0);
                oacc[1][df] = __builtin_amdgcn_mfma_f32_16x16x32_bf16(pa1, vf, oacc[1][df], 0, 0, 0);
            }
        }
        __syncthreads();
    }
    if (lane < 16) { r_lds[wq][l15] = 1.f / lsum[0]; r_lds[wq][16 + l15] = 1.f / lsum[1]; }
    __syncthreads();
#pragma unroll
    for (int mf = 0; mf < 2; ++mf) {
        float4 lv = *(const float4*)&r_lds[wq][mf * 16 + lh * 4];
        const float li[4] = { lv.x, lv.y, lv.z, lv.w };
#pragma unroll
        for (int df = 0; df < 2; ++df)
#pragma unroll
            for (int i = 0; i < 4; ++i) {
                int gq = q0 + mf * 16 + lh * 4 + i;
                int gd = df * 16 + l15;
                ctxb[((size_t)(b * SS) + gq) * DD + h * HDIM + gd] = f2bf(oacc[mf][df][i] * li[i]);
            }
    }
}

// ---------------- head: fp32 partial GEMV + reduce ----------------
__global__ __launch_bounds__(256) void k_head_part(
    const float* __restrict__ x, const float* __restrict__ W,
    float* __restrict__ part) {
    __shared__ float xs[16 * HEAD_KC];
    int c = blockIdx.x;
    int k0 = c * HEAD_KC;
    int t = threadIdx.x;
#pragma unroll
    for (int b = 0; b < 16; ++b)
        xs[b * HEAD_KC + t] = x[(size_t)b * SD + k0 + t];
    __syncthreads();
    int n4 = t * 4;
    float acc[16][4] = {};
#pragma unroll 4
    for (int k = 0; k < HEAD_KC; ++k) {
        float4 w = *(const float4*)&W[(size_t)(k0 + k) * NSOUT + n4];
#pragma unroll
        for (int b = 0; b < 16; ++b) {
            float xv = xs[b * HEAD_KC + k];
            acc[b][0] += xv * w.x; acc[b][1] += xv * w.y;
            acc[b][2] += xv * w.z; acc[b][3] += xv * w.w;
        }
    }
#pragma unroll
    for (int b = 0; b < 16; ++b) {
        float4 o = {acc[b][0], acc[b][1], acc[b][2], acc[b][3]};
        *(float4*)&part[((size_t)c * 16 + b) * NSOUT + n4] = o;
    }
}

__global__ __launch_bounds__(256) void k_head_reduce(
    const float* __restrict__ part, const float* __restrict__ hb,
    float* __restrict__ out) {
    int i = (blockIdx.x * 256 + threadIdx.x) * 4;
    float4 s = {0.f, 0.f, 0.f, 0.f};
#pragma unroll 8
    for (int c = 0; c < HEAD_NCH; ++c) {
        float4 p = *(const float4*)&part[(size_t)c * (16 * NSOUT) + i];
        s.x += p.x; s.y += p.y; s.z += p.z; s.w += p.w;
    }
    int n = i & (NSOUT - 1);
    float4 b4 = *(const float4*)&hb[n];
    float4 o = {s.x + b4.x, s.y + b4.y, s.z + b4.z, s.w + b4.w};
    *(float4*)&out[i] = o;
}

extern "C" void kernel_launch(void* const* d_in, const int* in_sizes, int n_in,
                              void* d_out, int out_size, void* d_ws, size_t ws_size,
                              hipStream_t stream) {
    const float* values = (const float*)d_in[0];
    const float* dib    = (const float*)d_in[1];
    const float* gamma  = (const float*)d_in[2];
    const float* mtyp   = (const float*)d_in[3];
    const int*   mask   = (const int*)d_in[4];
    const float* in_w   = (const float*)d_in[5];
    const float* in_b   = (const float*)d_in[6];
    const float* ln1_s  = (const float*)d_in[7];
    const float* ln1_b  = (const float*)d_in[8];
    const float* p_qw   = (const float*)d_in[9];
    const float* p_qb   = (const float*)d_in[10];
    const float* p_kw   = (const float*)d_in[11];
    const float* p_kb   = (const float*)d_in[12];
    const float* p_vw   = (const float*)d_in[13];
    const float* p_vb   = (const float*)d_in[14];
    const float* p_ow   = (const float*)d_in[15];
    const float* p_ob   = (const float*)d_in[16];
    const float* ln2_s  = (const float*)d_in[17];
    const float* ln2_b  = (const float*)d_in[18];
    const float* p_f1w  = (const float*)d_in[19];
    const float* p_f1b  = (const float*)d_in[20];
    const float* p_f2w  = (const float*)d_in[21];
    const float* p_f2b  = (const float*)d_in[22];
    const float* fn_s   = (const float*)d_in[23];
    const float* fn_b   = (const float*)d_in[24];
    const float* head_w = (const float*)d_in[25];
    const float* head_b = (const float*)d_in[26];
    float* out = (float*)d_out;

    const size_t MB = 1u << 20;
    char* w = (char*)d_ws;
    float* x    = (float*)(w + 0 * MB);            // 8 MB fp32 residual stream
    float* qf   = (float*)(w + 8 * MB);            // 8 MB final-LN fp32 out
    unsigned short* h16  = (unsigned short*)(w + 32 * MB);  // 4 MB each
    unsigned short* q16  = (unsigned short*)(w + 36 * MB);
    unsigned short* k16  = (unsigned short*)(w + 40 * MB);
    unsigned short* vt16 = (unsigned short*)(w + 44 * MB);
    unsigned short* cx16 = (unsigned short*)(w + 48 * MB);
    unsigned short* f116 = (unsigned short*)(w + 52 * MB);  // 16 MB
    unsigned short* wq16 = (unsigned short*)(w + 68 * MB);  // 256 KB each (2 layers)
    unsigned short* wk16 = (unsigned short*)(w + 68 * MB + 256 * 1024);
    unsigned short* wv16 = (unsigned short*)(w + 68 * MB + 512 * 1024);
    unsigned short* wo16 = (unsigned short*)(w + 68 * MB + 768 * 1024);
    unsigned short* wf116 = (unsigned short*)(w + 69 * MB); // 1 MB
    unsigned short* wf216 = (unsigned short*)(w + 70 * MB); // 1 MB
    float* ct   = (float*)(w + 71 * MB);
    float* st   = (float*)(w + 71 * MB + 64 * 1024);
    float* sc   = (float*)(w + 72 * MB);           // head partials (33.5 MB)

    k_rope_table<<<32, 256, 0, stream>>>(ct, st);
    k_prep_t<<<dim3(8, 8, NL), 256, 0, stream>>>(p_qw, wq16, DD, DD);
    k_prep_t<<<dim3(8, 8, NL), 256, 0, stream>>>(p_kw, wk16, DD, DD);
    k_prep_t<<<dim3(8, 8, NL), 256, 0, stream>>>(p_vw, wv16, DD, DD);
    k_prep_t<<<dim3(8, 8, NL), 256, 0, stream>>>(p_ow, wo16, DD, DD);
    k_prep_t<<<dim3(8, 32, NL), 256, 0, stream>>>(p_f1w, wf116, DD, FFD);
    k_prep_t<<<dim3(32, 8, NL), 256, 0, stream>>>(p_f2w, wf216, FFD, DD);
    k_input_proj<<<8192, 256, 0, stream>>>(values, dib, gamma, mtyp, in_w, in_b, x);

    for (int l = 0; l < NL; ++l) {
        k_layernorm<true><<<ROWS, 256, 0, stream>>>(x, h16, ln1_s + l * DD, ln1_b + l * DD);
        k_qkv<<<dim3(64, 6), 256, 0, stream>>>((const short*)h16,
            (const short*)(wq16 + l * 65536), (const short*)(wk16 + l * 65536),
            (const short*)(wv16 + l * 65536),
            p_qb + l * DD, p_kb + l * DD, p_vb + l * DD, ct, st, q16, k16, vt16);
        k_flash<<<dim3(4, BB * HH), 256, 0, stream>>>((const short*)q16, (const short*)k16,
            (const short*)vt16, mask, cx16);
        k_gemm64<2><<<dim3(128, 2), 256, 0, stream>>>((const short*)cx16,
            (const short*)(wo16 + l * 65536), p_ob + l * DD, x, ROWS, DD, DD, x, mask);
        k_layernorm<true><<<ROWS, 256, 0, stream>>>(x, h16, ln2_s + l * DD, ln2_b + l * DD);
        k_gemm_bf16<1, true><<<dim3(64, 8), 256, 0, stream>>>((const short*)h16,
            (const short*)(wf116 + l * 262144), p_f1b + l * FFD, f116,
            ROWS, FFD, DD, nullptr, nullptr);
        k_gemm64<3><<<dim3(128, 2), 256, 0, stream>>>((const short*)f116,
            (const short*)(wf216 + l * 262144), p_f2b + l * DD, x, ROWS, DD, FFD, x, nullptr);
    }

    k_layernorm<false><<<ROWS, 256, 0, stream>>>(x, qf, fn_s, fn_b);
    k_head_part<<<HEAD_NCH, 256, 0, stream>>>(qf, head_w, sc);
    k_head_reduce<<<16, 256, 0, stream>>>(sc, head_b, out);
}

// Round 7
// 365.257 us; speedup vs baseline: 3.4280x; 1.0159x over previous
//
#include <hip/hip_runtime.h>
#include <math.h>

#define BB 16
#define SS 512
#define DD 256
#define HH 8
#define HDIM 32
#define FFD 1024
#define NL 2
#define NSOUT 1024
#define SD (SS*DD)      // 131072
#define ROWS (BB*SS)    // 8192

#define HEAD_KC 256
#define HEAD_NCH 512    // SD / HEAD_KC

typedef __attribute__((ext_vector_type(8))) short short8;
typedef __attribute__((ext_vector_type(4))) float f32x4;

__device__ __forceinline__ unsigned short f2bf(float f) {
    union { float f; unsigned u; } c; c.f = f;
    unsigned u = c.u + 0x7fffu + ((c.u >> 16) & 1u);
    return (unsigned short)(u >> 16);
}

// ---------------- one-shot prep: all weight transposes + rope tables ----------------
__global__ __launch_bounds__(256) void k_prep_all(
    const float* __restrict__ p_qw, const float* __restrict__ p_kw,
    const float* __restrict__ p_vw, const float* __restrict__ p_ow,
    const float* __restrict__ p_f1w, const float* __restrict__ p_f2w,
    unsigned short* __restrict__ wq, unsigned short* __restrict__ wk,
    unsigned short* __restrict__ wv, unsigned short* __restrict__ wo,
    unsigned short* __restrict__ wf1, unsigned short* __restrict__ wf2,
    float* __restrict__ ct, float* __restrict__ st) {
    int bid = blockIdx.x;
    int t = threadIdx.x;
    if (bid >= 1536) {   // rope tables
        int i = (bid - 1536) * 256 + t;
        if (i < SS * 16) {
            int s = i >> 4, f = i & 15;
            float invf = powf(10000.f, -(float)f / 16.f);
            float ang = (float)s * invf;
            ct[i] = cosf(ang);
            st[i] = sinf(ang);
        }
        return;
    }
    const float* src; unsigned short* dst;
    int K, N, kx, nx, l;
    if (bid < 512) {
        int grp = bid >> 7, r = bid & 127; l = r >> 6; int tl = r & 63;
        kx = tl >> 3; nx = tl & 7; K = DD; N = DD;
        src = grp == 0 ? p_qw : grp == 1 ? p_kw : grp == 2 ? p_vw : p_ow;
        dst = grp == 0 ? wq : grp == 1 ? wk : grp == 2 ? wv : wo;
    } else if (bid < 1024) {
        int r = bid - 512; l = r >> 8; int tl = r & 255;
        kx = tl >> 5; nx = tl & 31; K = DD; N = FFD; src = p_f1w; dst = wf1;
    } else {
        int r = bid - 1024; l = r >> 8; int tl = r & 255;
        kx = tl >> 3; nx = tl & 7; K = FFD; N = DD; src = p_f2w; dst = wf2;
    }
    __shared__ float tile[32][33];
    size_t zo = (size_t)l * K * N;
    int k0 = kx * 32, n0 = nx * 32;
    int r_ = t >> 3, c4 = (t & 7) * 4;
    float4 a = *(const float4*)&src[zo + (size_t)(k0 + r_) * N + n0 + c4];
    tile[r_][c4 + 0] = a.x; tile[r_][c4 + 1] = a.y; tile[r_][c4 + 2] = a.z; tile[r_][c4 + 3] = a.w;
    __syncthreads();
    unsigned o0 = f2bf(tile[c4 + 0][r_]), o1 = f2bf(tile[c4 + 1][r_]);
    unsigned o2 = f2bf(tile[c4 + 2][r_]), o3 = f2bf(tile[c4 + 3][r_]);
    uint2 ud = { o0 | (o1 << 16), o2 | (o3 << 16) };
    *(uint2*)&dst[zo + (size_t)(n0 + r_) * K + k0 + c4] = ud;
}

// ---------------- input features + projection (fp32 x) ----------------
__global__ __launch_bounds__(256) void k_input_proj(
    const float* __restrict__ values, const float* __restrict__ dib,
    const float* __restrict__ gamma, const float* __restrict__ mtyp,
    const float* __restrict__ in_w, const float* __restrict__ in_b,
    float* __restrict__ x) {
    int i = blockIdx.x * 256 + threadIdx.x;
    int row = i >> 8, d = i & 255;
    float v = values[row];
    float f0 = (v >= 0.f) ? 1.f : -1.f;
    float f1 = fabsf(v);
    float f2 = gamma[row];
    float f3 = dib[row];
    float f4 = mtyp[row] * 2.f - 1.f;
    x[i] = f0 * in_w[d] + f1 * in_w[DD + d] + f2 * in_w[2 * DD + d]
         + f3 * in_w[3 * DD + d] + f4 * in_w[4 * DD + d] + in_b[d];
}

// ---------------- wave-per-row layernorm over D=256, no barriers ----------------
template <bool OBF>
__global__ __launch_bounds__(256) void k_layernorm_w(
    const float* __restrict__ in, void* __restrict__ outp,
    const float* __restrict__ sc, const float* __restrict__ bi) {
    int t = threadIdx.x, lane = t & 63, w = t >> 6;
    int row = blockIdx.x * 4 + w;
    float4 v = *(const float4*)&in[(size_t)row * DD + lane * 4];
    float s1 = v.x + v.y + v.z + v.w;
    float s2 = v.x * v.x + v.y * v.y + v.z * v.z + v.w * v.w;
#pragma unroll
    for (int off = 32; off > 0; off >>= 1) {
        s1 += __shfl_xor(s1, off);
        s2 += __shfl_xor(s2, off);
    }
    float mean = s1 * (1.f / DD);
    float var = s2 * (1.f / DD) - mean * mean;
    float rstd = rsqrtf(var + 1e-5f);
    float4 sv = *(const float4*)&sc[lane * 4];
    float4 bv = *(const float4*)&bi[lane * 4];
    float o0 = (v.x - mean) * rstd * sv.x + bv.x;
    float o1 = (v.y - mean) * rstd * sv.y + bv.y;
    float o2 = (v.z - mean) * rstd * sv.z + bv.z;
    float o3 = (v.w - mean) * rstd * sv.w + bv.w;
    if (OBF) {
        ushort4 u = { f2bf(o0), f2bf(o1), f2bf(o2), f2bf(o3) };
        *(ushort4*)&((unsigned short*)outp)[(size_t)row * DD + lane * 4] = u;
    } else {
        float4 o = { o0, o1, o2, o3 };
        *(float4*)&((float*)outp)[(size_t)row * DD + lane * 4] = o;
    }
}

// ---------------- bf16 MFMA GEMM 128x128 (FF1): C = A@Bt^T + bias, exact GELU, bf16 out
__global__ __launch_bounds__(256) void k_gemm_ff1(
    const short* __restrict__ A, const short* __restrict__ Bt,
    const float* __restrict__ bias, unsigned short* __restrict__ Cout,
    int M, int N, int K) {
    __shared__ __align__(16) short As[128 * 32];
    __shared__ __align__(16) short Bs[128 * 32];
    int t = threadIdx.x;
    int lane = t & 63, wid = t >> 6;
    int wr = wid >> 1, wc = wid & 1;
    int m0 = blockIdx.x * 128, n0 = blockIdx.y * 128;
    f32x4 acc[4][4] = {};
    int srow = t >> 2, sslot = t & 3;
    for (int k0 = 0; k0 < K; k0 += 32) {
#pragma unroll
        for (int p = 0; p < 2; ++p) {
            int row = srow + p * 64;
            int sw = sslot ^ ((row >> 1) & 3);
            *(float4*)&As[row * 32 + sw * 8] =
                *(const float4*)&A[(size_t)(m0 + row) * K + k0 + sslot * 8];
            *(float4*)&Bs[row * 32 + sw * 8] =
                *(const float4*)&Bt[(size_t)(n0 + row) * K + k0 + sslot * 8];
        }
        __syncthreads();
        short8 af[4], bfr[4];
#pragma unroll
        for (int mt = 0; mt < 4; ++mt) {
            int row = wr * 64 + mt * 16 + (lane & 15);
            int sl = (lane >> 4) ^ ((row >> 1) & 3);
            af[mt] = *(const short8*)&As[row * 32 + sl * 8];
        }
#pragma unroll
        for (int nt = 0; nt < 4; ++nt) {
            int row = wc * 64 + nt * 16 + (lane & 15);
            int sl = (lane >> 4) ^ ((row >> 1) & 3);
            bfr[nt] = *(const short8*)&Bs[row * 32 + sl * 8];
        }
#pragma unroll
        for (int mt = 0; mt < 4; ++mt)
#pragma unroll
            for (int nt = 0; nt < 4; ++nt)
                acc[mt][nt] = __builtin_amdgcn_mfma_f32_16x16x32_bf16(af[mt], bfr[nt], acc[mt][nt], 0, 0, 0);
        __syncthreads();
    }
#pragma unroll
    for (int mt = 0; mt < 4; ++mt) {
#pragma unroll
        for (int i = 0; i < 4; ++i) {
            int gm = m0 + wr * 64 + mt * 16 + (lane >> 4) * 4 + i;
#pragma unroll
            for (int nt = 0; nt < 4; ++nt) {
                int gn = n0 + wc * 64 + nt * 16 + (lane & 15);
                float v = acc[mt][nt][i] + bias[gn];
                v = 0.5f * v * (1.f + erff(v * 0.70710678118654752f));
                Cout[(size_t)gm * N + gn] = f2bf(v);
            }
        }
    }
}

// ---------------- bf16 MFMA GEMM 64x128, K_STEP=64 (O-proj / FF2), fp32 residual out
// EPI: 2 residual+row-mask into resx, 3 plain residual
template <int EPI>
__global__ __launch_bounds__(256) void k_gemm64(
    const short* __restrict__ A, const short* __restrict__ Bt,
    const float* __restrict__ bias, float* __restrict__ Cout,
    int M, int N, int K, const float* __restrict__ resx, const int* __restrict__ mask) {
    __shared__ __align__(16) short As[64 * 64];    // 8 KB
    __shared__ __align__(16) short Bs[128 * 64];   // 16 KB
    int t = threadIdx.x;
    int lane = t & 63, wid = t >> 6;
    int wr = wid >> 1, wc = wid & 1;          // wave: 32 rows x 64 cols
    int m0 = blockIdx.x * 64, n0 = blockIdx.y * 128;
    int l15 = lane & 15, lh = lane >> 4;
    f32x4 acc[2][4] = {};
    for (int k0 = 0; k0 < K; k0 += 64) {
#pragma unroll
        for (int p = 0; p < 2; ++p) {
            int idx = t + p * 256;
            int row = idx >> 3, sl = idx & 7;
            int sw = sl ^ (row & 7);
            *(float4*)&As[row * 64 + sw * 8] =
                *(const float4*)&A[(size_t)(m0 + row) * K + k0 + sl * 8];
        }
#pragma unroll
        for (int p = 0; p < 4; ++p) {
            int idx = t + p * 256;
            int row = idx >> 3, sl = idx & 7;
            int sw = sl ^ (row & 7);
            *(float4*)&Bs[row * 64 + sw * 8] =
                *(const float4*)&Bt[(size_t)(n0 + row) * K + k0 + sl * 8];
        }
        __syncthreads();
#pragma unroll
        for (int kk = 0; kk < 2; ++kk) {
            short8 af[2], bfr[4];
#pragma unroll
            for (int mt = 0; mt < 2; ++mt) {
                int row = wr * 32 + mt * 16 + l15;
                int sl = (kk * 4 + lh) ^ (row & 7);
                af[mt] = *(const short8*)&As[row * 64 + sl * 8];
            }
#pragma unroll
            for (int nt = 0; nt < 4; ++nt) {
                int row = wc * 64 + nt * 16 + l15;
                int sl = (kk * 4 + lh) ^ (row & 7);
                bfr[nt] = *(const short8*)&Bs[row * 64 + sl * 8];
            }
#pragma unroll
            for (int mt = 0; mt < 2; ++mt)
#pragma unroll
                for (int nt = 0; nt < 4; ++nt)
                    acc[mt][nt] = __builtin_amdgcn_mfma_f32_16x16x32_bf16(af[mt], bfr[nt], acc[mt][nt], 0, 0, 0);
        }
        __syncthreads();
    }
#pragma unroll
    for (int mt = 0; mt < 2; ++mt) {
#pragma unroll
        for (int i = 0; i < 4; ++i) {
            int gm = m0 + wr * 32 + mt * 16 + lh * 4 + i;
            float mk = 1.f;
            if (EPI == 2) mk = (mask[gm] != 0) ? 1.f : 0.f;
#pragma unroll
            for (int nt = 0; nt < 4; ++nt) {
                int gn = n0 + wc * 64 + nt * 16 + l15;
                float v = acc[mt][nt][i] + bias[gn];
                v = resx[(size_t)gm * N + gn] + v * mk;
                Cout[(size_t)gm * N + gn] = v;
            }
        }
    }
}

// ---------------- fused QKV GEMM (64x128 tiles) + bias + RoPE(+scale) / V-transpose --
// grid (M/64, 6): blockIdx.y>>1 selects Q/K/V, &1 selects col half.
__global__ __launch_bounds__(256) void k_qkv64(
    const short* __restrict__ A,
    const short* __restrict__ Wq, const short* __restrict__ Wk, const short* __restrict__ Wv,
    const float* __restrict__ bq, const float* __restrict__ bk, const float* __restrict__ bv,
    const float* __restrict__ ct, const float* __restrict__ st,
    unsigned short* __restrict__ q16, unsigned short* __restrict__ k16,
    unsigned short* __restrict__ vt16) {
    __shared__ __align__(16) short As[64 * 32];
    __shared__ __align__(16) short Bs[128 * 32];
    int mat = blockIdx.y >> 1;
    int n0 = (blockIdx.y & 1) * 128;
    const short* Bt = (mat == 0) ? Wq : (mat == 1) ? Wk : Wv;
    const float* bias = (mat == 0) ? bq : (mat == 1) ? bk : bv;
    int t = threadIdx.x;
    int lane = t & 63, wid = t >> 6;
    int wr = wid >> 1, wc = wid & 1;
    int m0 = blockIdx.x * 64;
    int l15 = lane & 15, lh = lane >> 4;
    f32x4 acc[2][4] = {};
    int srow = t >> 2, sslot = t & 3;
    for (int k0 = 0; k0 < DD; k0 += 32) {
        {
            int sw = sslot ^ ((srow >> 1) & 3);
            *(float4*)&As[srow * 32 + sw * 8] =
                *(const float4*)&A[(size_t)(m0 + srow) * DD + k0 + sslot * 8];
        }
#pragma unroll
        for (int p = 0; p < 2; ++p) {
            int row = srow + p * 64;
            int sw = sslot ^ ((row >> 1) & 3);
            *(float4*)&Bs[row * 32 + sw * 8] =
                *(const float4*)&Bt[(size_t)(n0 + row) * DD + k0 + sslot * 8];
        }
        __syncthreads();
        short8 af[2], bfr[4];
#pragma unroll
        for (int mt = 0; mt < 2; ++mt) {
            int row = wr * 32 + mt * 16 + l15;
            int sl = lh ^ ((row >> 1) & 3);
            af[mt] = *(const short8*)&As[row * 32 + sl * 8];
        }
#pragma unroll
        for (int nt = 0; nt < 4; ++nt) {
            int row = wc * 64 + nt * 16 + l15;
            int sl = lh ^ ((row >> 1) & 3);
            bfr[nt] = *(const short8*)&Bs[row * 32 + sl * 8];
        }
#pragma unroll
        for (int mt = 0; mt < 2; ++mt)
#pragma unroll
            for (int nt = 0; nt < 4; ++nt)
                acc[mt][nt] = __builtin_amdgcn_mfma_f32_16x16x32_bf16(af[mt], bfr[nt], acc[mt][nt], 0, 0, 0);
        __syncthreads();
    }
    float bs[4];
#pragma unroll
    for (int nt = 0; nt < 4; ++nt) bs[nt] = bias[n0 + wc * 64 + nt * 16 + l15];
    if (mat < 2) {
        unsigned short* dst = (mat == 0) ? q16 : k16;
        const float qscale = (mat == 0) ? 0.17677669529663687f : 1.f;  // fold 1/sqrt(32) into Q
#pragma unroll
        for (int mt = 0; mt < 2; ++mt) {
#pragma unroll
            for (int i = 0; i < 4; ++i) {
                int gm = m0 + wr * 32 + mt * 16 + lh * 4 + i;
                int s = gm & (SS - 1);
                float c = ct[s * 16 + l15], sn = st[s * 16 + l15];
                float val[4];
#pragma unroll
                for (int nt = 0; nt < 4; ++nt) val[nt] = (acc[mt][nt][i] + bs[nt]) * qscale;
#pragma unroll
                for (int nt = 0; nt < 4; ++nt) {
                    float partner = val[nt ^ 1];
                    float o = ((nt & 1) == 0) ? (val[nt] * c - partner * sn)
                                              : (val[nt] * c + partner * sn);
                    dst[(size_t)gm * DD + n0 + wc * 64 + nt * 16 + l15] = f2bf(o);
                }
            }
        }
    } else {
#pragma unroll
        for (int mt = 0; mt < 2; ++mt) {
            int gmb = m0 + wr * 32 + mt * 16 + lh * 4;
            int b = gmb >> 9, sb = gmb & (SS - 1);
#pragma unroll
            for (int nt = 0; nt < 4; ++nt) {
                int gn = n0 + wc * 64 + nt * 16 + l15;
                int h = gn >> 5, d = gn & 31;
                ushort4 u;
#pragma unroll
                for (int i = 0; i < 4; ++i)
                    (&u.x)[i] = f2bf(acc[mt][nt][i] + bs[nt]);
                *(ushort4*)&vt16[((size_t)((b * HH + h) * HDIM + d)) * SS + sb] = u;
            }
        }
    }
}

// ---------------- fused flash attention (Q pre-scaled) ----------------
__global__ __launch_bounds__(256) void k_flash(
    const short* __restrict__ qb, const short* __restrict__ kb,
    const short* __restrict__ vt, const int* __restrict__ mask,
    unsigned short* __restrict__ ctxb) {
    __shared__ float bias_lds[SS];
    __shared__ __align__(16) short p_lds[4][32 * 72];
    __shared__ __align__(16) float r_lds[4][32];
    int t = threadIdx.x, lane = t & 63, wq = t >> 6;
    int bh = blockIdx.y;
    int b = bh >> 3, h = bh & 7;
    int q0 = blockIdx.x * 128 + wq * 32;
    bias_lds[t]       = (mask[b * SS + t]       != 0) ? 0.f : -3.0e38f;
    bias_lds[t + 256] = (mask[b * SS + t + 256] != 0) ? 0.f : -3.0e38f;
    __syncthreads();
    int l15 = lane & 15, lh = lane >> 4;
    short8 qfr[2];
    qfr[0] = *(const short8*)&qb[((size_t)(b * SS) + q0 + l15) * DD + h * HDIM + lh * 8];
    qfr[1] = *(const short8*)&qb[((size_t)(b * SS) + q0 + 16 + l15) * DD + h * HDIM + lh * 8];
    float m[2] = {-3.0e38f, -3.0e38f};
    float lsum[2] = {0.f, 0.f};
    f32x4 oacc[2][2] = {};   // [mf = q-frag][df = d-frag]
    for (int k0 = 0; k0 < SS; k0 += 64) {
        f32x4 sT[4][2];
#pragma unroll
        for (int kt = 0; kt < 4; ++kt) {
            short8 kf = *(const short8*)&kb[((size_t)(b * SS) + k0 + kt * 16 + l15) * DD + h * HDIM + lh * 8];
#pragma unroll
            for (int qf = 0; qf < 2; ++qf) {
                f32x4 z = {0.f, 0.f, 0.f, 0.f};
                sT[kt][qf] = __builtin_amdgcn_mfma_f32_16x16x32_bf16(kf, qfr[qf], z, 0, 0, 0);
            }
        }
        float p[2][16];
        float r[2];
#pragma unroll
        for (int qf = 0; qf < 2; ++qf) {
            float pmax = -3.0e38f;
#pragma unroll
            for (int kt = 0; kt < 4; ++kt)
#pragma unroll
                for (int i = 0; i < 4; ++i) {
                    float s = sT[kt][qf][i] + bias_lds[k0 + kt * 16 + lh * 4 + i];
                    p[qf][kt * 4 + i] = s;
                    pmax = fmaxf(pmax, s);
                }
            pmax = fmaxf(pmax, __shfl_xor(pmax, 16));
            pmax = fmaxf(pmax, __shfl_xor(pmax, 32));
            float mn = fmaxf(m[qf], pmax);
            r[qf] = __expf(m[qf] - mn);
            m[qf] = mn;
            float cs = 0.f;
#pragma unroll
            for (int j = 0; j < 16; ++j) {
                float e = __expf(p[qf][j] - mn);
                p[qf][j] = e;
                cs += e;
            }
            cs += __shfl_xor(cs, 16);
            cs += __shfl_xor(cs, 32);
            lsum[qf] = lsum[qf] * r[qf] + cs;
        }
#pragma unroll
        for (int qf = 0; qf < 2; ++qf) {
            int qq = qf * 16 + l15;
#pragma unroll
            for (int kt = 0; kt < 4; ++kt) {
                unsigned u0 = (unsigned)f2bf(p[qf][kt * 4 + 0]) | ((unsigned)f2bf(p[qf][kt * 4 + 1]) << 16);
                unsigned u1 = (unsigned)f2bf(p[qf][kt * 4 + 2]) | ((unsigned)f2bf(p[qf][kt * 4 + 3]) << 16);
                uint2 u = { u0, u1 };
                *(uint2*)&p_lds[wq][qq * 72 + kt * 16 + lh * 4] = u;
            }
        }
        if (lane < 16) { r_lds[wq][l15] = r[0]; r_lds[wq][16 + l15] = r[1]; }
        __syncthreads();
#pragma unroll
        for (int mf = 0; mf < 2; ++mf) {
            float4 rv = *(const float4*)&r_lds[wq][mf * 16 + lh * 4];
#pragma unroll
            for (int df = 0; df < 2; ++df) {
                oacc[mf][df][0] *= rv.x; oacc[mf][df][1] *= rv.y;
                oacc[mf][df][2] *= rv.z; oacc[mf][df][3] *= rv.w;
            }
        }
#pragma unroll
        for (int ks = 0; ks < 2; ++ks) {
            short8 pa0 = *(const short8*)&p_lds[wq][(l15) * 72 + ks * 32 + lh * 8];
            short8 pa1 = *(const short8*)&p_lds[wq][(16 + l15) * 72 + ks * 32 + lh * 8];
#pragma unroll
            for (int df = 0; df < 2; ++df) {
                short8 vf = *(const short8*)&vt[((size_t)bh * HDIM + df * 16 + l15) * SS + k0 + ks * 32 + lh * 8];
                oacc[0][df] = __builtin_amdgcn_mfma_f32_16x16x32_bf16(pa0, vf, oacc[0][df], 0, 0, 0);
                oacc[1][df] = __builtin_amdgcn_mfma_f32_16x16x32_bf16(pa1, vf, oacc[1][df], 0, 0, 0);
            }
        }
        __syncthreads();
    }
    if (lane < 16) { r_lds[wq][l15] = 1.f / lsum[0]; r_lds[wq][16 + l15] = 1.f / lsum[1]; }
    __syncthreads();
#pragma unroll
    for (int mf = 0; mf < 2; ++mf) {
        float4 lv = *(const float4*)&r_lds[wq][mf * 16 + lh * 4];
        const float li[4] = { lv.x, lv.y, lv.z, lv.w };
#pragma unroll
        for (int df = 0; df < 2; ++df)
#pragma unroll
            for (int i = 0; i < 4; ++i) {
                int gq = q0 + mf * 16 + lh * 4 + i;
                int gd = df * 16 + l15;
                ctxb[((size_t)(b * SS) + gq) * DD + h * HDIM + gd] = f2bf(oacc[mf][df][i] * li[i]);
            }
    }
}

// ---------------- head: fp32 partial GEMV (nontemporal W stream) + reduce ------------
__global__ __launch_bounds__(256) void k_head_part(
    const float* __restrict__ x, const float* __restrict__ W,
    float* __restrict__ part) {
    __shared__ float xs[16 * HEAD_KC];
    int c = blockIdx.x;
    int k0 = c * HEAD_KC;
    int t = threadIdx.x;
#pragma unroll
    for (int b = 0; b < 16; ++b)
        xs[b * HEAD_KC + t] = x[(size_t)b * SD + k0 + t];
    __syncthreads();
    int n4 = t * 4;
    float acc[16][4] = {};
#pragma unroll 8
    for (int k = 0; k < HEAD_KC; ++k) {
        f32x4 w = __builtin_nontemporal_load((const f32x4*)&W[(size_t)(k0 + k) * NSOUT + n4]);
#pragma unroll
        for (int b = 0; b < 16; ++b) {
            float xv = xs[b * HEAD_KC + k];
            acc[b][0] += xv * w[0]; acc[b][1] += xv * w[1];
            acc[b][2] += xv * w[2]; acc[b][3] += xv * w[3];
        }
    }
#pragma unroll
    for (int b = 0; b < 16; ++b) {
        float4 o = {acc[b][0], acc[b][1], acc[b][2], acc[b][3]};
        *(float4*)&part[((size_t)c * 16 + b) * NSOUT + n4] = o;
    }
}

__global__ __launch_bounds__(256) void k_head_reduce(
    const float* __restrict__ part, const float* __restrict__ hb,
    float* __restrict__ out) {
    int i = (blockIdx.x * 256 + threadIdx.x) * 4;
    float4 s = {0.f, 0.f, 0.f, 0.f};
#pragma unroll 8
    for (int c = 0; c < HEAD_NCH; ++c) {
        float4 p = *(const float4*)&part[(size_t)c * (16 * NSOUT) + i];
        s.x += p.x; s.y += p.y; s.z += p.z; s.w += p.w;
    }
    int n = i & (NSOUT - 1);
    float4 b4 = *(const float4*)&hb[n];
    float4 o = {s.x + b4.x, s.y + b4.y, s.z + b4.z, s.w + b4.w};
    *(float4*)&out[i] = o;
}

extern "C" void kernel_launch(void* const* d_in, const int* in_sizes, int n_in,
                              void* d_out, int out_size, void* d_ws, size_t ws_size,
                              hipStream_t stream) {
    const float* values = (const float*)d_in[0];
    const float* dib    = (const float*)d_in[1];
    const float* gamma  = (const float*)d_in[2];
    const float* mtyp   = (const float*)d_in[3];
    const int*   mask   = (const int*)d_in[4];
    const float* in_w   = (const float*)d_in[5];
    const float* in_b   = (const float*)d_in[6];
    const float* ln1_s  = (const float*)d_in[7];
    const float* ln1_b  = (const float*)d_in[8];
    const float* p_qw   = (const float*)d_in[9];
    const float* p_qb   = (const float*)d_in[10];
    const float* p_kw   = (const float*)d_in[11];
    const float* p_kb   = (const float*)d_in[12];
    const float* p_vw   = (const float*)d_in[13];
    const float* p_vb   = (const float*)d_in[14];
    const float* p_ow   = (const float*)d_in[15];
    const float* p_ob   = (const float*)d_in[16];
    const float* ln2_s  = (const float*)d_in[17];
    const float* ln2_b  = (const float*)d_in[18];
    const float* p_f1w  = (const float*)d_in[19];
    const float* p_f1b  = (const float*)d_in[20];
    const float* p_f2w  = (const float*)d_in[21];
    const float* p_f2b  = (const float*)d_in[22];
    const float* fn_s   = (const float*)d_in[23];
    const float* fn_b   = (const float*)d_in[24];
    const float* head_w = (const float*)d_in[25];
    const float* head_b = (const float*)d_in[26];
    float* out = (float*)d_out;

    const size_t MB = 1u << 20;
    char* w = (char*)d_ws;
    float* x    = (float*)(w + 0 * MB);            // 8 MB fp32 residual stream
    float* qf   = (float*)(w + 8 * MB);            // 8 MB final-LN fp32 out
    unsigned short* h16  = (unsigned short*)(w + 32 * MB);  // 4 MB each
    unsigned short* q16  = (unsigned short*)(w + 36 * MB);
    unsigned short* k16  = (unsigned short*)(w + 40 * MB);
    unsigned short* vt16 = (unsigned short*)(w + 44 * MB);
    unsigned short* cx16 = (unsigned short*)(w + 48 * MB);
    unsigned short* f116 = (unsigned short*)(w + 52 * MB);  // 16 MB
    unsigned short* wq16 = (unsigned short*)(w + 68 * MB);  // 256 KB each (2 layers)
    unsigned short* wk16 = (unsigned short*)(w + 68 * MB + 256 * 1024);
    unsigned short* wv16 = (unsigned short*)(w + 68 * MB + 512 * 1024);
    unsigned short* wo16 = (unsigned short*)(w + 68 * MB + 768 * 1024);
    unsigned short* wf116 = (unsigned short*)(w + 69 * MB); // 1 MB
    unsigned short* wf216 = (unsigned short*)(w + 70 * MB); // 1 MB
    float* ct   = (float*)(w + 71 * MB);
    float* st   = (float*)(w + 71 * MB + 64 * 1024);
    float* sc   = (float*)(w + 72 * MB);           // head partials (33.5 MB)

    k_prep_all<<<1568, 256, 0, stream>>>(p_qw, p_kw, p_vw, p_ow, p_f1w, p_f2w,
                                         wq16, wk16, wv16, wo16, wf116, wf216, ct, st);
    k_input_proj<<<8192, 256, 0, stream>>>(values, dib, gamma, mtyp, in_w, in_b, x);

    for (int l = 0; l < NL; ++l) {
        k_layernorm_w<true><<<2048, 256, 0, stream>>>(x, h16, ln1_s + l * DD, ln1_b + l * DD);
        k_qkv64<<<dim3(128, 6), 256, 0, stream>>>((const short*)h16,
            (const short*)(wq16 + l * 65536), (const short*)(wk16 + l * 65536),
            (const short*)(wv16 + l * 65536),
            p_qb + l * DD, p_kb + l * DD, p_vb + l * DD, ct, st, q16, k16, vt16);
        k_flash<<<dim3(4, BB * HH), 256, 0, stream>>>((const short*)q16, (const short*)k16,
            (const short*)vt16, mask, cx16);
        k_gemm64<2><<<dim3(128, 2), 256, 0, stream>>>((const short*)cx16,
            (const short*)(wo16 + l * 65536), p_ob + l * DD, x, ROWS, DD, DD, x, mask);
        k_layernorm_w<true><<<2048, 256, 0, stream>>>(x, h16, ln2_s + l * DD, ln2_b + l * DD);
        k_gemm_ff1<<<dim3(64, 8), 256, 0, stream>>>((const short*)h16,
            (const short*)(wf116 + l * 262144), p_f1b + l * FFD, f116, ROWS, FFD, DD);
        k_gemm64<3><<<dim3(128, 2), 256, 0, stream>>>((const short*)f116,
            (const short*)(wf216 + l * 262144), p_f2b + l * DD, x, ROWS, DD, FFD, x, nullptr);
    }

    k_layernorm_w<false><<<2048, 256, 0, stream>>>(x, qf, fn_s, fn_b);
    k_head_part<<<HEAD_NCH, 256, 0, stream>>>(qf, head_w, sc);
    k_head_reduce<<<16, 256, 0, stream>>>(sc, head_b, out);
}

// Round 8
// 344.916 us; speedup vs baseline: 3.6302x; 1.0590x over previous
//
#include <hip/hip_runtime.h>
#include <math.h>

#define BB 16
#define SS 512
#define DD 256
#define HH 8
#define HDIM 32
#define FFD 1024
#define NL 2
#define NSOUT 1024
#define SD (SS*DD)      // 131072
#define ROWS (BB*SS)    // 8192

#define HEAD_KC 256
#define HEAD_NCH 512    // SD / HEAD_KC

typedef __attribute__((ext_vector_type(8))) short short8;
typedef __attribute__((ext_vector_type(4))) float f32x4;

__device__ __forceinline__ unsigned short f2bf(float f) {
    union { float f; unsigned u; } c; c.f = f;
    unsigned u = c.u + 0x7fffu + ((c.u >> 16) & 1u);
    return (unsigned short)(u >> 16);
}

// ---------------- one-shot prep: all weight transposes + rope tables ----------------
__global__ __launch_bounds__(256) void k_prep_all(
    const float* __restrict__ p_qw, const float* __restrict__ p_kw,
    const float* __restrict__ p_vw, const float* __restrict__ p_ow,
    const float* __restrict__ p_f1w, const float* __restrict__ p_f2w,
    unsigned short* __restrict__ wq, unsigned short* __restrict__ wk,
    unsigned short* __restrict__ wv, unsigned short* __restrict__ wo,
    unsigned short* __restrict__ wf1, unsigned short* __restrict__ wf2,
    float* __restrict__ ct, float* __restrict__ st) {
    int bid = blockIdx.x;
    int t = threadIdx.x;
    if (bid >= 1536) {   // rope tables
        int i = (bid - 1536) * 256 + t;
        if (i < SS * 16) {
            int s = i >> 4, f = i & 15;
            float invf = powf(10000.f, -(float)f / 16.f);
            float ang = (float)s * invf;
            ct[i] = cosf(ang);
            st[i] = sinf(ang);
        }
        return;
    }
    const float* src; unsigned short* dst;
    int K, N, kx, nx, l;
    if (bid < 512) {
        int grp = bid >> 7, r = bid & 127; l = r >> 6; int tl = r & 63;
        kx = tl >> 3; nx = tl & 7; K = DD; N = DD;
        src = grp == 0 ? p_qw : grp == 1 ? p_kw : grp == 2 ? p_vw : p_ow;
        dst = grp == 0 ? wq : grp == 1 ? wk : grp == 2 ? wv : wo;
    } else if (bid < 1024) {
        int r = bid - 512; l = r >> 8; int tl = r & 255;
        kx = tl >> 5; nx = tl & 31; K = DD; N = FFD; src = p_f1w; dst = wf1;
    } else {
        int r = bid - 1024; l = r >> 8; int tl = r & 255;
        kx = tl >> 3; nx = tl & 7; K = FFD; N = DD; src = p_f2w; dst = wf2;
    }
    __shared__ float tile[32][33];
    size_t zo = (size_t)l * K * N;
    int k0 = kx * 32, n0 = nx * 32;
    int r_ = t >> 3, c4 = (t & 7) * 4;
    float4 a = *(const float4*)&src[zo + (size_t)(k0 + r_) * N + n0 + c4];
    tile[r_][c4 + 0] = a.x; tile[r_][c4 + 1] = a.y; tile[r_][c4 + 2] = a.z; tile[r_][c4 + 3] = a.w;
    __syncthreads();
    unsigned o0 = f2bf(tile[c4 + 0][r_]), o1 = f2bf(tile[c4 + 1][r_]);
    unsigned o2 = f2bf(tile[c4 + 2][r_]), o3 = f2bf(tile[c4 + 3][r_]);
    uint2 ud = { o0 | (o1 << 16), o2 | (o3 << 16) };
    *(uint2*)&dst[zo + (size_t)(n0 + r_) * K + k0 + c4] = ud;
}

// ---------------- input features + projection (fp32 x), float4 ----------------
__global__ __launch_bounds__(256) void k_input_proj(
    const float* __restrict__ values, const float* __restrict__ dib,
    const float* __restrict__ gamma, const float* __restrict__ mtyp,
    const float* __restrict__ in_w, const float* __restrict__ in_b,
    float* __restrict__ x) {
    int i = blockIdx.x * 256 + threadIdx.x;   // ROWS*64
    int row = i >> 6, d4 = (i & 63) * 4;
    float v = values[row];
    float f0 = (v >= 0.f) ? 1.f : -1.f;
    float f1 = fabsf(v);
    float f2 = gamma[row];
    float f3 = dib[row];
    float f4 = mtyp[row] * 2.f - 1.f;
    float4 w0 = *(const float4*)&in_w[d4];
    float4 w1 = *(const float4*)&in_w[DD + d4];
    float4 w2 = *(const float4*)&in_w[2 * DD + d4];
    float4 w3 = *(const float4*)&in_w[3 * DD + d4];
    float4 w4 = *(const float4*)&in_w[4 * DD + d4];
    float4 bb = *(const float4*)&in_b[d4];
    float4 o;
    o.x = f0 * w0.x + f1 * w1.x + f2 * w2.x + f3 * w3.x + f4 * w4.x + bb.x;
    o.y = f0 * w0.y + f1 * w1.y + f2 * w2.y + f3 * w3.y + f4 * w4.y + bb.y;
    o.z = f0 * w0.z + f1 * w1.z + f2 * w2.z + f3 * w3.z + f4 * w4.z + bb.z;
    o.w = f0 * w0.w + f1 * w1.w + f2 * w2.w + f3 * w3.w + f4 * w4.w + bb.w;
    *(float4*)&x[(size_t)row * DD + d4] = o;
}

// ---------------- wave-per-row layernorm over D=256, no barriers ----------------
template <bool OBF>
__global__ __launch_bounds__(256) void k_layernorm_w(
    const float* __restrict__ in, void* __restrict__ outp,
    const float* __restrict__ sc, const float* __restrict__ bi) {
    int t = threadIdx.x, lane = t & 63, w = t >> 6;
    int row = blockIdx.x * 4 + w;
    float4 v = *(const float4*)&in[(size_t)row * DD + lane * 4];
    float s1 = v.x + v.y + v.z + v.w;
    float s2 = v.x * v.x + v.y * v.y + v.z * v.z + v.w * v.w;
#pragma unroll
    for (int off = 32; off > 0; off >>= 1) {
        s1 += __shfl_xor(s1, off);
        s2 += __shfl_xor(s2, off);
    }
    float mean = s1 * (1.f / DD);
    float var = s2 * (1.f / DD) - mean * mean;
    float rstd = rsqrtf(var + 1e-5f);
    float4 sv = *(const float4*)&sc[lane * 4];
    float4 bv = *(const float4*)&bi[lane * 4];
    float o0 = (v.x - mean) * rstd * sv.x + bv.x;
    float o1 = (v.y - mean) * rstd * sv.y + bv.y;
    float o2 = (v.z - mean) * rstd * sv.z + bv.z;
    float o3 = (v.w - mean) * rstd * sv.w + bv.w;
    if (OBF) {
        ushort4 u = { f2bf(o0), f2bf(o1), f2bf(o2), f2bf(o3) };
        *(ushort4*)&((unsigned short*)outp)[(size_t)row * DD + lane * 4] = u;
    } else {
        float4 o = { o0, o1, o2, o3 };
        *(float4*)&((float*)outp)[(size_t)row * DD + lane * 4] = o;
    }
}

// ---------------- bf16 MFMA GEMM 128x128 (FF1): C = A@Bt^T + bias, exact GELU, bf16 out
__global__ __launch_bounds__(256) void k_gemm_ff1(
    const short* __restrict__ A, const short* __restrict__ Bt,
    const float* __restrict__ bias, unsigned short* __restrict__ Cout,
    int M, int N, int K) {
    __shared__ __align__(16) short As[128 * 32];
    __shared__ __align__(16) short Bs[128 * 32];
    int t = threadIdx.x;
    int lane = t & 63, wid = t >> 6;
    int wr = wid >> 1, wc = wid & 1;
    int m0 = blockIdx.x * 128, n0 = blockIdx.y * 128;
    f32x4 acc[4][4] = {};
    int srow = t >> 2, sslot = t & 3;
    for (int k0 = 0; k0 < K; k0 += 32) {
#pragma unroll
        for (int p = 0; p < 2; ++p) {
            int row = srow + p * 64;
            int sw = sslot ^ ((row >> 1) & 3);
            *(float4*)&As[row * 32 + sw * 8] =
                *(const float4*)&A[(size_t)(m0 + row) * K + k0 + sslot * 8];
            *(float4*)&Bs[row * 32 + sw * 8] =
                *(const float4*)&Bt[(size_t)(n0 + row) * K + k0 + sslot * 8];
        }
        __syncthreads();
        short8 af[4], bfr[4];
#pragma unroll
        for (int mt = 0; mt < 4; ++mt) {
            int row = wr * 64 + mt * 16 + (lane & 15);
            int sl = (lane >> 4) ^ ((row >> 1) & 3);
            af[mt] = *(const short8*)&As[row * 32 + sl * 8];
        }
#pragma unroll
        for (int nt = 0; nt < 4; ++nt) {
            int row = wc * 64 + nt * 16 + (lane & 15);
            int sl = (lane >> 4) ^ ((row >> 1) & 3);
            bfr[nt] = *(const short8*)&Bs[row * 32 + sl * 8];
        }
#pragma unroll
        for (int mt = 0; mt < 4; ++mt)
#pragma unroll
            for (int nt = 0; nt < 4; ++nt)
                acc[mt][nt] = __builtin_amdgcn_mfma_f32_16x16x32_bf16(af[mt], bfr[nt], acc[mt][nt], 0, 0, 0);
        __syncthreads();
    }
#pragma unroll
    for (int mt = 0; mt < 4; ++mt) {
#pragma unroll
        for (int i = 0; i < 4; ++i) {
            int gm = m0 + wr * 64 + mt * 16 + (lane >> 4) * 4 + i;
#pragma unroll
            for (int nt = 0; nt < 4; ++nt) {
                int gn = n0 + wc * 64 + nt * 16 + (lane & 15);
                float v = acc[mt][nt][i] + bias[gn];
                v = 0.5f * v * (1.f + erff(v * 0.70710678118654752f));
                Cout[(size_t)gm * N + gn] = f2bf(v);
            }
        }
    }
}

// ---------------- bf16 MFMA GEMM 64x128, K_STEP=64 (O-proj / FF2), fp32 residual out
// EPI: 2 residual+row-mask into resx, 3 plain residual
template <int EPI>
__global__ __launch_bounds__(256) void k_gemm64(
    const short* __restrict__ A, const short* __restrict__ Bt,
    const float* __restrict__ bias, float* __restrict__ Cout,
    int M, int N, int K, const float* __restrict__ resx, const int* __restrict__ mask) {
    __shared__ __align__(16) short As[64 * 64];    // 8 KB
    __shared__ __align__(16) short Bs[128 * 64];   // 16 KB
    int t = threadIdx.x;
    int lane = t & 63, wid = t >> 6;
    int wr = wid >> 1, wc = wid & 1;          // wave: 32 rows x 64 cols
    int m0 = blockIdx.x * 64, n0 = blockIdx.y * 128;
    int l15 = lane & 15, lh = lane >> 4;
    f32x4 acc[2][4] = {};
    for (int k0 = 0; k0 < K; k0 += 64) {
#pragma unroll
        for (int p = 0; p < 2; ++p) {
            int idx = t + p * 256;
            int row = idx >> 3, sl = idx & 7;
            int sw = sl ^ (row & 7);
            *(float4*)&As[row * 64 + sw * 8] =
                *(const float4*)&A[(size_t)(m0 + row) * K + k0 + sl * 8];
        }
#pragma unroll
        for (int p = 0; p < 4; ++p) {
            int idx = t + p * 256;
            int row = idx >> 3, sl = idx & 7;
            int sw = sl ^ (row & 7);
            *(float4*)&Bs[row * 64 + sw * 8] =
                *(const float4*)&Bt[(size_t)(n0 + row) * K + k0 + sl * 8];
        }
        __syncthreads();
#pragma unroll
        for (int kk = 0; kk < 2; ++kk) {
            short8 af[2], bfr[4];
#pragma unroll
            for (int mt = 0; mt < 2; ++mt) {
                int row = wr * 32 + mt * 16 + l15;
                int sl = (kk * 4 + lh) ^ (row & 7);
                af[mt] = *(const short8*)&As[row * 64 + sl * 8];
            }
#pragma unroll
            for (int nt = 0; nt < 4; ++nt) {
                int row = wc * 64 + nt * 16 + l15;
                int sl = (kk * 4 + lh) ^ (row & 7);
                bfr[nt] = *(const short8*)&Bs[row * 64 + sl * 8];
            }
#pragma unroll
            for (int mt = 0; mt < 2; ++mt)
#pragma unroll
                for (int nt = 0; nt < 4; ++nt)
                    acc[mt][nt] = __builtin_amdgcn_mfma_f32_16x16x32_bf16(af[mt], bfr[nt], acc[mt][nt], 0, 0, 0);
        }
        __syncthreads();
    }
#pragma unroll
    for (int mt = 0; mt < 2; ++mt) {
#pragma unroll
        for (int i = 0; i < 4; ++i) {
            int gm = m0 + wr * 32 + mt * 16 + lh * 4 + i;
            float mk = 1.f;
            if (EPI == 2) mk = (mask[gm] != 0) ? 1.f : 0.f;
#pragma unroll
            for (int nt = 0; nt < 4; ++nt) {
                int gn = n0 + wc * 64 + nt * 16 + l15;
                float v = acc[mt][nt][i] + bias[gn];
                v = resx[(size_t)gm * N + gn] + v * mk;
                Cout[(size_t)gm * N + gn] = v;
            }
        }
    }
}

// ---------------- fused QKV GEMM (64x128 tiles) + bias + RoPE(+scale) / V-transpose --
__global__ __launch_bounds__(256) void k_qkv64(
    const short* __restrict__ A,
    const short* __restrict__ Wq, const short* __restrict__ Wk, const short* __restrict__ Wv,
    const float* __restrict__ bq, const float* __restrict__ bk, const float* __restrict__ bv,
    const float* __restrict__ ct, const float* __restrict__ st,
    unsigned short* __restrict__ q16, unsigned short* __restrict__ k16,
    unsigned short* __restrict__ vt16) {
    __shared__ __align__(16) short As[64 * 32];
    __shared__ __align__(16) short Bs[128 * 32];
    int mat = blockIdx.y >> 1;
    int n0 = (blockIdx.y & 1) * 128;
    const short* Bt = (mat == 0) ? Wq : (mat == 1) ? Wk : Wv;
    const float* bias = (mat == 0) ? bq : (mat == 1) ? bk : bv;
    int t = threadIdx.x;
    int lane = t & 63, wid = t >> 6;
    int wr = wid >> 1, wc = wid & 1;
    int m0 = blockIdx.x * 64;
    int l15 = lane & 15, lh = lane >> 4;
    f32x4 acc[2][4] = {};
    int srow = t >> 2, sslot = t & 3;
    for (int k0 = 0; k0 < DD; k0 += 32) {
        {
            int sw = sslot ^ ((srow >> 1) & 3);
            *(float4*)&As[srow * 32 + sw * 8] =
                *(const float4*)&A[(size_t)(m0 + srow) * DD + k0 + sslot * 8];
        }
#pragma unroll
        for (int p = 0; p < 2; ++p) {
            int row = srow + p * 64;
            int sw = sslot ^ ((row >> 1) & 3);
            *(float4*)&Bs[row * 32 + sw * 8] =
                *(const float4*)&Bt[(size_t)(n0 + row) * DD + k0 + sslot * 8];
        }
        __syncthreads();
        short8 af[2], bfr[4];
#pragma unroll
        for (int mt = 0; mt < 2; ++mt) {
            int row = wr * 32 + mt * 16 + l15;
            int sl = lh ^ ((row >> 1) & 3);
            af[mt] = *(const short8*)&As[row * 32 + sl * 8];
        }
#pragma unroll
        for (int nt = 0; nt < 4; ++nt) {
            int row = wc * 64 + nt * 16 + l15;
            int sl = lh ^ ((row >> 1) & 3);
            bfr[nt] = *(const short8*)&Bs[row * 32 + sl * 8];
        }
#pragma unroll
        for (int mt = 0; mt < 2; ++mt)
#pragma unroll
            for (int nt = 0; nt < 4; ++nt)
                acc[mt][nt] = __builtin_amdgcn_mfma_f32_16x16x32_bf16(af[mt], bfr[nt], acc[mt][nt], 0, 0, 0);
        __syncthreads();
    }
    float bs[4];
#pragma unroll
    for (int nt = 0; nt < 4; ++nt) bs[nt] = bias[n0 + wc * 64 + nt * 16 + l15];
    if (mat < 2) {
        unsigned short* dst = (mat == 0) ? q16 : k16;
        const float qscale = (mat == 0) ? 0.17677669529663687f : 1.f;  // fold 1/sqrt(32) into Q
#pragma unroll
        for (int mt = 0; mt < 2; ++mt) {
#pragma unroll
            for (int i = 0; i < 4; ++i) {
                int gm = m0 + wr * 32 + mt * 16 + lh * 4 + i;
                int s = gm & (SS - 1);
                float c = ct[s * 16 + l15], sn = st[s * 16 + l15];
                float val[4];
#pragma unroll
                for (int nt = 0; nt < 4; ++nt) val[nt] = (acc[mt][nt][i] + bs[nt]) * qscale;
#pragma unroll
                for (int nt = 0; nt < 4; ++nt) {
                    float partner = val[nt ^ 1];
                    float o = ((nt & 1) == 0) ? (val[nt] * c - partner * sn)
                                              : (val[nt] * c + partner * sn);
                    dst[(size_t)gm * DD + n0 + wc * 64 + nt * 16 + l15] = f2bf(o);
                }
            }
        }
    } else {
#pragma unroll
        for (int mt = 0; mt < 2; ++mt) {
            int gmb = m0 + wr * 32 + mt * 16 + lh * 4;
            int b = gmb >> 9, sb = gmb & (SS - 1);
#pragma unroll
            for (int nt = 0; nt < 4; ++nt) {
                int gn = n0 + wc * 64 + nt * 16 + l15;
                int h = gn >> 5, d = gn & 31;
                ushort4 u;
#pragma unroll
                for (int i = 0; i < 4; ++i)
                    (&u.x)[i] = f2bf(acc[mt][nt][i] + bs[nt]);
                *(ushort4*)&vt16[((size_t)((b * HH + h) * HDIM + d)) * SS + sb] = u;
            }
        }
    }
}

// ---------------- fused flash attention (Q pre-scaled) ----------------
__global__ __launch_bounds__(256) void k_flash(
    const short* __restrict__ qb, const short* __restrict__ kb,
    const short* __restrict__ vt, const int* __restrict__ mask,
    unsigned short* __restrict__ ctxb) {
    __shared__ float bias_lds[SS];
    __shared__ __align__(16) short p_lds[4][32 * 72];
    __shared__ __align__(16) float r_lds[4][32];
    int t = threadIdx.x, lane = t & 63, wq = t >> 6;
    int bh = blockIdx.y;
    int b = bh >> 3, h = bh & 7;
    int q0 = blockIdx.x * 128 + wq * 32;
    bias_lds[t]       = (mask[b * SS + t]       != 0) ? 0.f : -3.0e38f;
    bias_lds[t + 256] = (mask[b * SS + t + 256] != 0) ? 0.f : -3.0e38f;
    __syncthreads();
    int l15 = lane & 15, lh = lane >> 4;
    short8 qfr[2];
    qfr[0] = *(const short8*)&qb[((size_t)(b * SS) + q0 + l15) * DD + h * HDIM + lh * 8];
    qfr[1] = *(const short8*)&qb[((size_t)(b * SS) + q0 + 16 + l15) * DD + h * HDIM + lh * 8];
    float m[2] = {-3.0e38f, -3.0e38f};
    float lsum[2] = {0.f, 0.f};
    f32x4 oacc[2][2] = {};   // [mf = q-frag][df = d-frag]
    for (int k0 = 0; k0 < SS; k0 += 64) {
        f32x4 sT[4][2];
#pragma unroll
        for (int kt = 0; kt < 4; ++kt) {
            short8 kf = *(const short8*)&kb[((size_t)(b * SS) + k0 + kt * 16 + l15) * DD + h * HDIM + lh * 8];
#pragma unroll
            for (int qf = 0; qf < 2; ++qf) {
                f32x4 z = {0.f, 0.f, 0.f, 0.f};
                sT[kt][qf] = __builtin_amdgcn_mfma_f32_16x16x32_bf16(kf, qfr[qf], z, 0, 0, 0);
            }
        }
        float p[2][16];
        float r[2];
#pragma unroll
        for (int qf = 0; qf < 2; ++qf) {
            float pmax = -3.0e38f;
#pragma unroll
            for (int kt = 0; kt < 4; ++kt)
#pragma unroll
                for (int i = 0; i < 4; ++i) {
                    float s = sT[kt][qf][i] + bias_lds[k0 + kt * 16 + lh * 4 + i];
                    p[qf][kt * 4 + i] = s;
                    pmax = fmaxf(pmax, s);
                }
            pmax = fmaxf(pmax, __shfl_xor(pmax, 16));
            pmax = fmaxf(pmax, __shfl_xor(pmax, 32));
            float mn = fmaxf(m[qf], pmax);
            r[qf] = __expf(m[qf] - mn);
            m[qf] = mn;
            float cs = 0.f;
#pragma unroll
            for (int j = 0; j < 16; ++j) {
                float e = __expf(p[qf][j] - mn);
                p[qf][j] = e;
                cs += e;
            }
            cs += __shfl_xor(cs, 16);
            cs += __shfl_xor(cs, 32);
            lsum[qf] = lsum[qf] * r[qf] + cs;
        }
#pragma unroll
        for (int qf = 0; qf < 2; ++qf) {
            int qq = qf * 16 + l15;
#pragma unroll
            for (int kt = 0; kt < 4; ++kt) {
                unsigned u0 = (unsigned)f2bf(p[qf][kt * 4 + 0]) | ((unsigned)f2bf(p[qf][kt * 4 + 1]) << 16);
                unsigned u1 = (unsigned)f2bf(p[qf][kt * 4 + 2]) | ((unsigned)f2bf(p[qf][kt * 4 + 3]) << 16);
                uint2 u = { u0, u1 };
                *(uint2*)&p_lds[wq][qq * 72 + kt * 16 + lh * 4] = u;
            }
        }
        if (lane < 16) { r_lds[wq][l15] = r[0]; r_lds[wq][16 + l15] = r[1]; }
        __syncthreads();
#pragma unroll
        for (int mf = 0; mf < 2; ++mf) {
            float4 rv = *(const float4*)&r_lds[wq][mf * 16 + lh * 4];
#pragma unroll
            for (int df = 0; df < 2; ++df) {
                oacc[mf][df][0] *= rv.x; oacc[mf][df][1] *= rv.y;
                oacc[mf][df][2] *= rv.z; oacc[mf][df][3] *= rv.w;
            }
        }
#pragma unroll
        for (int ks = 0; ks < 2; ++ks) {
            short8 pa0 = *(const short8*)&p_lds[wq][(l15) * 72 + ks * 32 + lh * 8];
            short8 pa1 = *(const short8*)&p_lds[wq][(16 + l15) * 72 + ks * 32 + lh * 8];
#pragma unroll
            for (int df = 0; df < 2; ++df) {
                short8 vf = *(const short8*)&vt[((size_t)bh * HDIM + df * 16 + l15) * SS + k0 + ks * 32 + lh * 8];
                oacc[0][df] = __builtin_amdgcn_mfma_f32_16x16x32_bf16(pa0, vf, oacc[0][df], 0, 0, 0);
                oacc[1][df] = __builtin_amdgcn_mfma_f32_16x16x32_bf16(pa1, vf, oacc[1][df], 0, 0, 0);
            }
        }
        __syncthreads();
    }
    if (lane < 16) { r_lds[wq][l15] = 1.f / lsum[0]; r_lds[wq][16 + l15] = 1.f / lsum[1]; }
    __syncthreads();
#pragma unroll
    for (int mf = 0; mf < 2; ++mf) {
        float4 lv = *(const float4*)&r_lds[wq][mf * 16 + lh * 4];
        const float li[4] = { lv.x, lv.y, lv.z, lv.w };
#pragma unroll
        for (int df = 0; df < 2; ++df)
#pragma unroll
            for (int i = 0; i < 4; ++i) {
                int gq = q0 + mf * 16 + lh * 4 + i;
                int gd = df * 16 + l15;
                ctxb[((size_t)(b * SS) + gq) * DD + h * HDIM + gd] = f2bf(oacc[mf][df][i] * li[i]);
            }
    }
}

// ---------------- head: fused final-LN + fp32 partial GEMV (nontemporal W) ----------
// chunk c == sequence row s=c; LN over D=256 == exactly the staged slice.
__global__ __launch_bounds__(256) void k_head_part(
    const float* __restrict__ x, const float* __restrict__ fns, const float* __restrict__ fnb,
    const float* __restrict__ W, float* __restrict__ part) {
    __shared__ float xs[16 * HEAD_KC];
    int c = blockIdx.x;
    int t = threadIdx.x, lane = t & 63, w = t >> 6;
    float4 sv = *(const float4*)&fns[lane * 4];
    float4 bv = *(const float4*)&fnb[lane * 4];
#pragma unroll
    for (int rr = 0; rr < 4; ++rr) {
        int b = w * 4 + rr;
        float4 v = *(const float4*)&x[(size_t)b * SD + c * HEAD_KC + lane * 4];
        float s1 = v.x + v.y + v.z + v.w;
        float s2 = v.x * v.x + v.y * v.y + v.z * v.z + v.w * v.w;
#pragma unroll
        for (int off = 32; off > 0; off >>= 1) {
            s1 += __shfl_xor(s1, off);
            s2 += __shfl_xor(s2, off);
        }
        float mean = s1 * (1.f / DD);
        float var = s2 * (1.f / DD) - mean * mean;
        float rstd = rsqrtf(var + 1e-5f);
        float4 o;
        o.x = (v.x - mean) * rstd * sv.x + bv.x;
        o.y = (v.y - mean) * rstd * sv.y + bv.y;
        o.z = (v.z - mean) * rstd * sv.z + bv.z;
        o.w = (v.w - mean) * rstd * sv.w + bv.w;
        *(float4*)&xs[b * HEAD_KC + lane * 4] = o;
    }
    __syncthreads();
    int k0 = c * HEAD_KC;
    int n4 = t * 4;
    float acc[16][4] = {};
#pragma unroll 8
    for (int k = 0; k < HEAD_KC; ++k) {
        f32x4 wv = __builtin_nontemporal_load((const f32x4*)&W[(size_t)(k0 + k) * NSOUT + n4]);
#pragma unroll
        for (int b = 0; b < 16; ++b) {
            float xv = xs[b * HEAD_KC + k];
            acc[b][0] += xv * wv[0]; acc[b][1] += xv * wv[1];
            acc[b][2] += xv * wv[2]; acc[b][3] += xv * wv[3];
        }
    }
#pragma unroll
    for (int b = 0; b < 16; ++b) {
        float4 o = {acc[b][0], acc[b][1], acc[b][2], acc[b][3]};
        *(float4*)&part[((size_t)c * 16 + b) * NSOUT + n4] = o;
    }
}

// ---------------- head reduce: 64 blocks x 512 threads, 8 c-groups ----------------
__global__ __launch_bounds__(512) void k_head_reduce(
    const float* __restrict__ part, const float* __restrict__ hb,
    float* __restrict__ out) {
    __shared__ float red[8][260];
    int t = threadIdx.x;
    int col = t & 63;            // float4 column within the block's 256-output slice
    int grp = t >> 6;            // 0..7
    int base = blockIdx.x * 256; // 64 blocks x 256 outputs = 16384
    f32x4 s = {0.f, 0.f, 0.f, 0.f};
#pragma unroll 8
    for (int c = grp; c < HEAD_NCH; c += 8) {
        f32x4 p = *(const f32x4*)&part[(size_t)c * (16 * NSOUT) + base + col * 4];
        s[0] += p[0]; s[1] += p[1]; s[2] += p[2]; s[3] += p[3];
    }
    red[grp][col * 4 + 0] = s[0];
    red[grp][col * 4 + 1] = s[1];
    red[grp][col * 4 + 2] = s[2];
    red[grp][col * 4 + 3] = s[3];
    __syncthreads();
    if (t < 256) {
        float acc = 0.f;
#pragma unroll
        for (int g = 0; g < 8; ++g) acc += red[g][t];
        out[base + t] = acc + hb[(base + t) & (NSOUT - 1)];
    }
}

extern "C" void kernel_launch(void* const* d_in, const int* in_sizes, int n_in,
                              void* d_out, int out_size, void* d_ws, size_t ws_size,
                              hipStream_t stream) {
    const float* values = (const float*)d_in[0];
    const float* dib    = (const float*)d_in[1];
    const float* gamma  = (const float*)d_in[2];
    const float* mtyp   = (const float*)d_in[3];
    const int*   mask   = (const int*)d_in[4];
    const float* in_w   = (const float*)d_in[5];
    const float* in_b   = (const float*)d_in[6];
    const float* ln1_s  = (const float*)d_in[7];
    const float* ln1_b  = (const float*)d_in[8];
    const float* p_qw   = (const float*)d_in[9];
    const float* p_qb   = (const float*)d_in[10];
    const float* p_kw   = (const float*)d_in[11];
    const float* p_kb   = (const float*)d_in[12];
    const float* p_vw   = (const float*)d_in[13];
    const float* p_vb   = (const float*)d_in[14];
    const float* p_ow   = (const float*)d_in[15];
    const float* p_ob   = (const float*)d_in[16];
    const float* ln2_s  = (const float*)d_in[17];
    const float* ln2_b  = (const float*)d_in[18];
    const float* p_f1w  = (const float*)d_in[19];
    const float* p_f1b  = (const float*)d_in[20];
    const float* p_f2w  = (const float*)d_in[21];
    const float* p_f2b  = (const float*)d_in[22];
    const float* fn_s   = (const float*)d_in[23];
    const float* fn_b   = (const float*)d_in[24];
    const float* head_w = (const float*)d_in[25];
    const float* head_b = (const float*)d_in[26];
    float* out = (float*)d_out;

    const size_t MB = 1u << 20;
    char* w = (char*)d_ws;
    float* x    = (float*)(w + 0 * MB);            // 8 MB fp32 residual stream
    unsigned short* h16  = (unsigned short*)(w + 32 * MB);  // 4 MB each
    unsigned short* q16  = (unsigned short*)(w + 36 * MB);
    unsigned short* k16  = (unsigned short*)(w + 40 * MB);
    unsigned short* vt16 = (unsigned short*)(w + 44 * MB);
    unsigned short* cx16 = (unsigned short*)(w + 48 * MB);
    unsigned short* f116 = (unsigned short*)(w + 52 * MB);  // 16 MB
    unsigned short* wq16 = (unsigned short*)(w + 68 * MB);  // 256 KB each (2 layers)
    unsigned short* wk16 = (unsigned short*)(w + 68 * MB + 256 * 1024);
    unsigned short* wv16 = (unsigned short*)(w + 68 * MB + 512 * 1024);
    unsigned short* wo16 = (unsigned short*)(w + 68 * MB + 768 * 1024);
    unsigned short* wf116 = (unsigned short*)(w + 69 * MB); // 1 MB
    unsigned short* wf216 = (unsigned short*)(w + 70 * MB); // 1 MB
    float* ct   = (float*)(w + 71 * MB);
    float* st   = (float*)(w + 71 * MB + 64 * 1024);
    float* sc   = (float*)(w + 72 * MB);           // head partials (33.5 MB)

    k_prep_all<<<1568, 256, 0, stream>>>(p_qw, p_kw, p_vw, p_ow, p_f1w, p_f2w,
                                         wq16, wk16, wv16, wo16, wf116, wf216, ct, st);
    k_input_proj<<<2048, 256, 0, stream>>>(values, dib, gamma, mtyp, in_w, in_b, x);

    for (int l = 0; l < NL; ++l) {
        k_layernorm_w<true><<<2048, 256, 0, stream>>>(x, h16, ln1_s + l * DD, ln1_b + l * DD);
        k_qkv64<<<dim3(128, 6), 256, 0, stream>>>((const short*)h16,
            (const short*)(wq16 + l * 65536), (const short*)(wk16 + l * 65536),
            (const short*)(wv16 + l * 65536),
            p_qb + l * DD, p_kb + l * DD, p_vb + l * DD, ct, st, q16, k16, vt16);
        k_flash<<<dim3(4, BB * HH), 256, 0, stream>>>((const short*)q16, (const short*)k16,
            (const short*)vt16, mask, cx16);
        k_gemm64<2><<<dim3(128, 2), 256, 0, stream>>>((const short*)cx16,
            (const short*)(wo16 + l * 65536), p_ob + l * DD, x, ROWS, DD, DD, x, mask);
        k_layernorm_w<true><<<2048, 256, 0, stream>>>(x, h16, ln2_s + l * DD, ln2_b + l * DD);
        k_gemm_ff1<<<dim3(64, 8), 256, 0, stream>>>((const short*)h16,
            (const short*)(wf116 + l * 262144), p_f1b + l * FFD, f116, ROWS, FFD, DD);
        k_gemm64<3><<<dim3(128, 2), 256, 0, stream>>>((const short*)f116,
            (const short*)(wf216 + l * 262144), p_f2b + l * DD, x, ROWS, DD, FFD, x, nullptr);
    }

    k_head_part<<<HEAD_NCH, 256, 0, stream>>>(x, fn_s, fn_b, head_w, sc);
    k_head_reduce<<<64, 512, 0, stream>>>(sc, head_b, out);
}